// Round 3
// baseline (586.511 us; speedup 1.0000x reference)
//
#include <hip/hip_runtime.h>
#include <math.h>

// GAT 2-layer, N=100K nodes, E=1.6M edges (+N self loops), fp32 compute,
// f16 feature rows for the edge gather.
// CSR build via 2-level bucket sort (bucket = dst>>8).
// agg: 8 lanes per dst node, 8 nodes per wave, f16 pair-dot (v_dot2_f32_f16).
//   NEW: degree-sorted node assignment (perm) so the 8 nodes of a wave have
//   near-equal degree (kills max-of-8 trip-count divergence); quad unroll
//   (4 gathers in flight, 2 acc chains); agg1 writes f16 out1 rows (stride
//   64) which gemm2 consumes directly.
// gemm1 MFMA: 3-pass truncation-split bf16 (x_hi@W_hi + x_lo@W_hi + x_hi@W_lo).

constexpr int F_IN = 128;
constexpr int F_H  = 64;
constexpr int F_O  = 40;
constexpr int NBMAX = 512;      // max buckets (N <= 131072)
constexpr int CHUNK = 8192;     // edges per block in k_binC
constexpr int DCLS  = 64;       // degree classes for counting sort

using h2 = decltype(__builtin_amdgcn_cvt_pkrtz(0.f, 0.f));   // <2 x half>
typedef __attribute__((ext_vector_type(4))) float f32x4;
typedef __attribute__((ext_vector_type(8))) short s16x8;

__device__ __forceinline__ h2 u2h(unsigned u) { return __builtin_bit_cast(h2, u); }

__device__ __forceinline__ float fdot2f(h2 a, h2 b, float c) {
#if __has_builtin(__builtin_amdgcn_fdot2)
    return __builtin_amdgcn_fdot2(a, b, c, false);      // v_dot2_f32_f16
#else
    return c + (float)a.x * (float)b.x + (float)a.y * (float)b.y;
#endif
}
// interleave two u32s of packed f16 pairs: pklo -> (b.lo16, a.lo16), pkhi -> (b.hi16, a.hi16)
__device__ __forceinline__ h2 pklo(unsigned a, unsigned b) {
    return u2h(__builtin_amdgcn_perm(a, b, 0x05040100u));
}
__device__ __forceinline__ h2 pkhi(unsigned a, unsigned b) {
    return u2h(__builtin_amdgcn_perm(a, b, 0x07060302u));
}
__device__ __forceinline__ unsigned short f2h(float f) {   // RNE f32->f16 bits
    _Float16 x = (_Float16)f;
    return __builtin_bit_cast(unsigned short, x);
}

// ---------------- CSR build: bucket sort ----------------

__global__ __launch_bounds__(256) void k_binA(const int* __restrict__ dsts,
                                              int* __restrict__ bcnt,
                                              int E, int Et, int NB) {
    __shared__ int hist[NBMAX];
    for (int i = threadIdx.x; i < NB; i += 256) hist[i] = 0;
    __syncthreads();
    int e0 = blockIdx.x * 2048;
#pragma unroll
    for (int it = 0; it < 8; ++it) {
        int e = e0 + it * 256 + threadIdx.x;
        if (e < Et) {
            int d = (e < E) ? dsts[e] : (e - E);
            atomicAdd(&hist[d >> 8], 1);
        }
    }
    __syncthreads();
    for (int i = threadIdx.x; i < NB; i += 256) {
        int c = hist[i];
        if (c) atomicAdd(&bcnt[i], c);
    }
}

__global__ __launch_bounds__(NBMAX) void k_binB(const int* __restrict__ bcnt,
                                                int* __restrict__ bbase,
                                                int* __restrict__ bcur,
                                                int* __restrict__ rp,
                                                int NB, int N, int Et) {
    __shared__ int sc[NBMAX];
    int t = threadIdx.x;
    int v = (t < NB) ? bcnt[t] : 0;
    sc[t] = v; __syncthreads();
    int x = v;
    for (int o = 1; o < NBMAX; o <<= 1) {
        int y = (t >= o) ? sc[t - o] : 0;
        __syncthreads();
        x += y;
        sc[t] = x;
        __syncthreads();
    }
    if (t < NB) { int b = x - v; bbase[t] = b; bcur[t] = b; }
    if (t == 0) rp[N] = Et;
}

__global__ __launch_bounds__(256) void k_binC(const int* __restrict__ srcs,
                                              const int* __restrict__ dsts,
                                              int* __restrict__ bcur,
                                              unsigned* __restrict__ binned,
                                              int E, int Et, int NB) {
    __shared__ int hist[NBMAX];
    __shared__ int gbase[NBMAX];
    __shared__ int lcnt[NBMAX];
    int t = threadIdx.x;
    for (int i = t; i < NB; i += 256) hist[i] = 0;
    __syncthreads();
    int e0 = blockIdx.x * CHUNK;
#pragma unroll 4
    for (int it = 0; it < CHUNK / 256; ++it) {
        int e = e0 + it * 256 + t;
        if (e < Et) {
            int d = (e < E) ? dsts[e] : (e - E);
            atomicAdd(&hist[d >> 8], 1);
        }
    }
    __syncthreads();
    for (int i = t; i < NB; i += 256) {
        int c = hist[i];
        gbase[i] = c ? atomicAdd(&bcur[i], c) : 0;
        lcnt[i] = 0;
    }
    __syncthreads();
#pragma unroll 4
    for (int it = 0; it < CHUNK / 256; ++it) {
        int e = e0 + it * 256 + t;
        if (e < Et) {
            int s, d;
            if (e < E) { s = srcs[e]; d = dsts[e]; } else { s = e - E; d = s; }
            int b = d >> 8;
            int p = atomicAdd(&lcnt[b], 1);
            binned[gbase[b] + p] = (unsigned)s | ((unsigned)(d & 255) << 24);
        }
    }
}

__global__ __launch_bounds__(256) void k_binD(const unsigned* __restrict__ binned,
                                              const int* __restrict__ bbase,
                                              const int* __restrict__ bcur,
                                              int* __restrict__ rp,
                                              int* __restrict__ csr, int N) {
    __shared__ int hist[256];
    __shared__ int sc[256];
    __shared__ int lcnt[256];
    int b = blockIdx.x, t = threadIdx.x;
    int base = bbase[b], end = bcur[b];
    hist[t] = 0; __syncthreads();
    for (int j = base + t; j < end; j += 256)
        atomicAdd(&hist[binned[j] >> 24], 1);
    __syncthreads();
    int v = hist[t];
    sc[t] = v; __syncthreads();
    int x = v;
    for (int o = 1; o < 256; o <<= 1) {
        int y = (t >= o) ? sc[t - o] : 0;
        __syncthreads();
        x += y;
        sc[t] = x;
        __syncthreads();
    }
    int pref = x - v;
    int g = (b << 8) + t;
    if (g < N) rp[g] = base + pref;
    sc[t] = pref;
    lcnt[t] = 0;
    __syncthreads();
    for (int j = base + t; j < end; j += 256) {
        unsigned w = binned[j];
        int v2 = (int)(w >> 24);
        int s = (int)(w & 0xFFFFFFu);
        int p = atomicAdd(&lcnt[v2], 1);
        csr[base + sc[v2] + p] = s;
    }
}

// ---------------- degree counting sort -> perm ----------------

__global__ __launch_bounds__(256) void k_dsortA(const int* __restrict__ rp,
                                                int* __restrict__ dcnt, int N) {
    __shared__ int h[DCLS];
    if (threadIdx.x < DCLS) h[threadIdx.x] = 0;
    __syncthreads();
    int i = blockIdx.x * 256 + threadIdx.x;
    if (i < N) {
        int d = min(rp[i + 1] - rp[i], DCLS - 1);
        atomicAdd(&h[d], 1);
    }
    __syncthreads();
    if (threadIdx.x < DCLS) {
        int c = h[threadIdx.x];
        if (c) atomicAdd(&dcnt[threadIdx.x], c);
    }
}

__global__ __launch_bounds__(64) void k_dsortB(const int* __restrict__ dcnt,
                                               int* __restrict__ dcur) {
    int t = threadIdx.x;
    int v = dcnt[t];
    int x = v;
#pragma unroll
    for (int o = 1; o < 64; o <<= 1) {
        int y = __shfl_up(x, o);
        if (t >= o) x += y;
    }
    dcur[t] = x - v;                               // exclusive base
}

__global__ __launch_bounds__(256) void k_dsortC(const int* __restrict__ rp,
                                                int* __restrict__ dcur,
                                                int* __restrict__ perm, int N) {
    int i = blockIdx.x * 256 + threadIdx.x;
    if (i >= N) return;
    int d = min(rp[i + 1] - rp[i], DCLS - 1);
    int p = atomicAdd(&dcur[d], 1);
    perm[p] = i;
}

// ---------------- W1 split: fp32 [128][64] -> bf16-hi/lo transposed [64][128] ----------------

__global__ __launch_bounds__(256) void k_wsplit(const float* __restrict__ W,
                                                unsigned short* __restrict__ WhiT,
                                                unsigned short* __restrict__ WloT) {
    int i = blockIdx.x * 256 + threadIdx.x;
    if (i >= F_IN * F_H) return;
    int k = i >> 6, c = i & 63;                    // W[k][c], C = F_H = 64
    float w = W[i];
    unsigned u = __float_as_uint(w);
    unsigned hi = u & 0xFFFF0000u;                 // truncation split: residual
    float d = w - __uint_as_float(hi);             // captured exactly by lo
    WhiT[c * F_IN + k] = (unsigned short)(hi >> 16);
    WloT[c * F_IN + k] = (unsigned short)(__float_as_uint(d) >> 16);
}

// ---------------- GEMM1 (MFMA): h1 = f16(x @ W1), fused fp32 alphas ----------------

__global__ __launch_bounds__(256) void k_gemm1m(const float* __restrict__ x,
                                                const unsigned short* __restrict__ WhiT,
                                                const unsigned short* __restrict__ WloT,
                                                const float* __restrict__ avs,
                                                const float* __restrict__ avd,
                                                unsigned short* __restrict__ h,
                                                float* __restrict__ as,
                                                float* __restrict__ ad, int N) {
    __shared__ unsigned short hs[64][72];          // 72: bank-stagger, 16B-aligned rows
    const int t = threadIdx.x;
    const int wv = t >> 6;
    const int lane = t & 63;
    const int lrow = lane & 15;
    const int lk8 = lane >> 4;
    const int r0 = blockIdx.x * 64;
    const int arow = r0 + wv * 16 + lrow;
    const float* xp = x + (size_t)min(arow, N - 1) * F_IN;

    // preload full row slice (8 float4), then split to bf16 hi/lo A-frags
    float4 xv0[4], xv1[4];
#pragma unroll
    for (int kt = 0; kt < 4; ++kt) {
        xv0[kt] = *(const float4*)&xp[kt * 32 + lk8 * 8];
        xv1[kt] = *(const float4*)&xp[kt * 32 + lk8 * 8 + 4];
    }
    s16x8 ah[4], al[4];
#pragma unroll
    for (int kt = 0; kt < 4; ++kt) {
        float e0[8] = {xv0[kt].x, xv0[kt].y, xv0[kt].z, xv0[kt].w,
                       xv1[kt].x, xv1[kt].y, xv1[kt].z, xv1[kt].w};
        unsigned uh[4], ul[4];
#pragma unroll
        for (int p = 0; p < 4; ++p) {
            float a0 = e0[2 * p], a1 = e0[2 * p + 1];
            unsigned u0 = __float_as_uint(a0), u1 = __float_as_uint(a1);
            float d0 = a0 - __uint_as_float(u0 & 0xFFFF0000u);
            float d1 = a1 - __uint_as_float(u1 & 0xFFFF0000u);
            uh[p] = __builtin_amdgcn_perm(u1, u0, 0x07060302u);
            ul[p] = __builtin_amdgcn_perm(__float_as_uint(d1), __float_as_uint(d0), 0x07060302u);
        }
        ah[kt] = __builtin_bit_cast(s16x8, make_uint4(uh[0], uh[1], uh[2], uh[3]));
        al[kt] = __builtin_bit_cast(s16x8, make_uint4(ul[0], ul[1], ul[2], ul[3]));
    }

    f32x4 acc[4] = {};                             // one 16x16 C-tile per ct
#pragma unroll
    for (int kt = 0; kt < 4; ++kt) {
#pragma unroll
        for (int ct = 0; ct < 4; ++ct) {
            const int boff = (ct * 16 + lrow) * F_IN + kt * 32 + lk8 * 8;
            s16x8 bh = *(const s16x8*)&WhiT[boff];
            s16x8 bl = *(const s16x8*)&WloT[boff];
            acc[ct] = __builtin_amdgcn_mfma_f32_16x16x32_bf16(ah[kt], bh, acc[ct], 0, 0, 0);
            acc[ct] = __builtin_amdgcn_mfma_f32_16x16x32_bf16(al[kt], bh, acc[ct], 0, 0, 0);
            acc[ct] = __builtin_amdgcn_mfma_f32_16x16x32_bf16(ah[kt], bl, acc[ct], 0, 0, 0);
        }
    }

    // fused alphas from fp32 accumulators: reduce over 16 cols (lrow groups)
    float avs_c[4], avd_c[4];
#pragma unroll
    for (int ct = 0; ct < 4; ++ct) {
        avs_c[ct] = avs[ct * 16 + lrow];
        avd_c[ct] = avd[ct * 16 + lrow];
    }
#pragma unroll
    for (int r = 0; r < 4; ++r) {
        float ps = acc[0][r] * avs_c[0] + acc[1][r] * avs_c[1]
                 + acc[2][r] * avs_c[2] + acc[3][r] * avs_c[3];
        float pd = acc[0][r] * avd_c[0] + acc[1][r] * avd_c[1]
                 + acc[2][r] * avd_c[2] + acc[3][r] * avd_c[3];
#pragma unroll
        for (int o = 8; o; o >>= 1) {
            ps += __shfl_xor(ps, o, 16);
            pd += __shfl_xor(pd, o, 16);
        }
        int orow = r0 + wv * 16 + lk8 * 4 + r;
        if (lrow == 0 && orow < N) { as[orow] = ps; ad[orow] = pd; }
    }

    // C -> LDS (f16) -> coalesced global store
#pragma unroll
    for (int ct = 0; ct < 4; ++ct)
#pragma unroll
        for (int r = 0; r < 4; ++r)
            hs[wv * 16 + lk8 * 4 + r][ct * 16 + lrow] = f2h(acc[ct][r]);
    __syncthreads();
    const int row = t >> 2, ch = t & 3;
    const int grow = r0 + row;
    if (grow < N) {
        uint4 v0 = *(const uint4*)&hs[row][ch * 16];
        uint4 v1 = *(const uint4*)&hs[row][ch * 16 + 8];
        uint4* gp = (uint4*)(h + (size_t)grow * F_H + ch * 16);
        gp[0] = v0; gp[1] = v1;
    }
}

// ---------------- GEMM2: h2 = f16(out1_f16 @ W2) padded to 64 cols ----------------

__global__ __launch_bounds__(256) void k_gemm2(const unsigned short* __restrict__ xin,
                                               const float* __restrict__ W,
                                               const float* __restrict__ avs,
                                               const float* __restrict__ avd,
                                               unsigned short* __restrict__ h,
                                               float* __restrict__ as,
                                               float* __restrict__ ad, int N) {
    __shared__ __align__(16) float Ws[F_H * F_O];
    for (int i = threadIdx.x; i < F_H * F_O; i += 256) Ws[i] = W[i];
    __syncthreads();
    int t = threadIdx.x;
    int r0 = blockIdx.x * 64 + (t >> 3) * 2;
    int l = t & 7;
    if (r0 >= N) return;
    const uint2* xa = (const uint2*)(xin + (size_t)r0 * F_H);
    const uint2* xb = (const uint2*)(xin + (size_t)(r0 + 1) * F_H);
    float acca[5] = {}, accb[5] = {};
#pragma unroll
    for (int k4 = 0; k4 < F_H / 4; ++k4) {
        uint2 ua = xa[k4];
        uint2 ub = xb[k4];
        h2 a01 = u2h(ua.x), a23 = u2h(ua.y);
        h2 b01 = u2h(ub.x), b23 = u2h(ub.y);
        float xva[4] = {(float)a01.x, (float)a01.y, (float)a23.x, (float)a23.y};
        float xvb[4] = {(float)b01.x, (float)b01.y, (float)b23.x, (float)b23.y};
        int kb = k4 * 4;
#pragma unroll
        for (int kk = 0; kk < 4; ++kk) {
            const float* wr = &Ws[(kb + kk) * F_O + l];
            float w0 = wr[0], w1 = wr[8], w2 = wr[16], w3 = wr[24], w4 = wr[32];
            float xs = xva[kk];
            acca[0] += xs * w0; acca[1] += xs * w1; acca[2] += xs * w2;
            acca[3] += xs * w3; acca[4] += xs * w4;
            float ys = xvb[kk];
            accb[0] += ys * w0; accb[1] += ys * w1; accb[2] += ys * w2;
            accb[3] += ys * w3; accb[4] += ys * w4;
        }
    }
    float psa = 0.f, pda = 0.f, psb = 0.f, pdb = 0.f;
    unsigned short* ra = h + (size_t)r0 * F_H;     // padded row stride 64
    unsigned short* rb = h + (size_t)(r0 + 1) * F_H;
#pragma unroll
    for (int cc = 0; cc < 5; ++cc) {
        int c = l + 8 * cc;
        ra[c] = f2h(acca[cc]);
        rb[c] = f2h(accb[cc]);
        float vs = avs[c], vd = avd[c];
        psa += acca[cc] * vs; pda += acca[cc] * vd;
        psb += accb[cc] * vs; pdb += accb[cc] * vd;
    }
#pragma unroll
    for (int pp = 0; pp < 3; ++pp) {               // zero pad cols 40..63
        int c = 40 + l * 3 + pp;
        ra[c] = 0; rb[c] = 0;
    }
#pragma unroll
    for (int o = 4; o; o >>= 1) {
        psa += __shfl_xor(psa, o, 8);
        pda += __shfl_xor(pda, o, 8);
        psb += __shfl_xor(psb, o, 8);
        pdb += __shfl_xor(pdb, o, 8);
    }
    if (l == 0) { as[r0] = psa; ad[r0] = pda; as[r0 + 1] = psb; ad[r0 + 1] = pdb; }
}

// ---------------- Aggregation: 8 lanes per dst node, 8 nodes per wave ----------------
// Degree-sorted perm -> uniform trip counts within a wave. Quad unroll:
// pad edge list to x4 (w=0), 4 gathers in flight per iteration, 2 acc chains.

template <int FOUT, bool RELU, bool LOGSM, bool F16OUT>
__global__ __launch_bounds__(256) void k_agg(const int* __restrict__ perm,
                                             const int* __restrict__ rp,
                                             const int* __restrict__ csr,
                                             const float* __restrict__ as,
                                             const float* __restrict__ ad,
                                             const uint4* __restrict__ h4,
                                             const float* __restrict__ bias,
                                             void* __restrict__ outv, int N) {
    constexpr int CAP = 64;                        // LDS-resident edges per node
    __shared__ __align__(16) uint2 wsb[4][8][CAP + 2];
    const int w = threadIdx.x >> 6;
    const int g = (threadIdx.x >> 3) & 7;
    const int c = threadIdx.x & 7;
    const int slot = blockIdx.x * 32 + (threadIdx.x >> 3);
    if (slot >= N) return;
    const int i = perm[slot];
    const int start = rp[i], end = rp[i + 1];
    const int deg = end - start;
    const int dm = min(deg, CAP);
    const int dmR4 = (dm + 3) & ~3;                // padded to x4 (<= CAP)
    const float adi = ad[i];

    // Phase A: compute edge weights into this group's LDS segment
    for (int idx = c; idx < dm; idx += 8) {
        int srcn = csr[start + idx];
        float e = as[srcn] + adi;
        e = fmaxf(e, 0.2f * e);                    // leaky_relu
        wsb[w][g][idx] = make_uint2(__float_as_uint(__expf(e)), (unsigned)srcn);
    }
    {   // pad (at most 3 entries): w=0, src=self
        int idx = dm + c;
        if (idx < dmR4) wsb[w][g][idx] = make_uint2(0u, (unsigned)i);
    }

    // Phase B: quad loop (same-wave LDS, no barrier needed)
    const uint4* pw = (const uint4*)wsb[w][g];
    float acc[8] = {}, acc2[8] = {};
    float sacc = 0.f;
    const int nquad = dmR4 >> 2;
    for (int q = 0; q < nquad; ++q) {
        uint4 t0 = pw[2 * q];                      // (w0,s0,w1,s1)
        uint4 t1 = pw[2 * q + 1];                  // (w2,s2,w3,s3)
        uint4 hv0 = h4[((unsigned)t0.y << 3) + c];
        uint4 hv1 = h4[((unsigned)t0.w << 3) + c];
        uint4 hv2 = h4[((unsigned)t1.y << 3) + c];
        uint4 hv3 = h4[((unsigned)t1.w << 3) + c];
        float w0 = __uint_as_float(t0.x), w1 = __uint_as_float(t0.z);
        float w2 = __uint_as_float(t1.x), w3 = __uint_as_float(t1.z);
        sacc += (w0 + w1) + (w2 + w3);
        h2 wp0 = __builtin_amdgcn_cvt_pkrtz(w0, w1);
        h2 wp1 = __builtin_amdgcn_cvt_pkrtz(w2, w3);
        acc[0] = fdot2f(wp0, pklo(hv1.x, hv0.x), acc[0]);
        acc[1] = fdot2f(wp0, pkhi(hv1.x, hv0.x), acc[1]);
        acc[2] = fdot2f(wp0, pklo(hv1.y, hv0.y), acc[2]);
        acc[3] = fdot2f(wp0, pkhi(hv1.y, hv0.y), acc[3]);
        acc[4] = fdot2f(wp0, pklo(hv1.z, hv0.z), acc[4]);
        acc[5] = fdot2f(wp0, pkhi(hv1.z, hv0.z), acc[5]);
        acc[6] = fdot2f(wp0, pklo(hv1.w, hv0.w), acc[6]);
        acc[7] = fdot2f(wp0, pkhi(hv1.w, hv0.w), acc[7]);
        acc2[0] = fdot2f(wp1, pklo(hv3.x, hv2.x), acc2[0]);
        acc2[1] = fdot2f(wp1, pkhi(hv3.x, hv2.x), acc2[1]);
        acc2[2] = fdot2f(wp1, pklo(hv3.y, hv2.y), acc2[2]);
        acc2[3] = fdot2f(wp1, pkhi(hv3.y, hv2.y), acc2[3]);
        acc2[4] = fdot2f(wp1, pklo(hv3.z, hv2.z), acc2[4]);
        acc2[5] = fdot2f(wp1, pkhi(hv3.z, hv2.z), acc2[5]);
        acc2[6] = fdot2f(wp1, pklo(hv3.w, hv2.w), acc2[6]);
        acc2[7] = fdot2f(wp1, pkhi(hv3.w, hv2.w), acc2[7]);
    }

    // rare overflow tail (deg > CAP): single-edge, dup-pair trick with (w,0)
    for (int j = start + dm; j < end; ++j) {
        int srcn = csr[j];
        float e = as[srcn] + adi;
        e = fmaxf(e, 0.2f * e);
        float wv = __expf(e);
        sacc += wv;
        uint4 hv = h4[((unsigned)srcn << 3) + c];
        h2 wp = __builtin_amdgcn_cvt_pkrtz(wv, 0.f);
        acc[0] = fdot2f(wp, pklo(hv.x, hv.x), acc[0]);
        acc[1] = fdot2f(wp, pkhi(hv.x, hv.x), acc[1]);
        acc[2] = fdot2f(wp, pklo(hv.y, hv.y), acc[2]);
        acc[3] = fdot2f(wp, pkhi(hv.y, hv.y), acc[3]);
        acc[4] = fdot2f(wp, pklo(hv.z, hv.z), acc[4]);
        acc[5] = fdot2f(wp, pkhi(hv.z, hv.z), acc[5]);
        acc[6] = fdot2f(wp, pklo(hv.w, hv.w), acc[6]);
        acc[7] = fdot2f(wp, pkhi(hv.w, hv.w), acc[7]);
    }

#pragma unroll
    for (int k = 0; k < 8; ++k) acc[k] += acc2[k];
    float inv = 1.f / sacc;                        // identical across the group

    if (!LOGSM) {
        float r[8];
#pragma unroll
        for (int k = 0; k < 8; ++k) {
            r[k] = fmaf(acc[k], inv, bias[8 * c + k]);
            if (RELU) r[k] = fmaxf(r[k], 0.f);
        }
        if (F16OUT) {                              // f16 rows, stride 64 (= F_H)
            unsigned short* oh = (unsigned short*)outv;
            unsigned u0 = (unsigned)f2h(r[0]) | ((unsigned)f2h(r[1]) << 16);
            unsigned u1 = (unsigned)f2h(r[2]) | ((unsigned)f2h(r[3]) << 16);
            unsigned u2 = (unsigned)f2h(r[4]) | ((unsigned)f2h(r[5]) << 16);
            unsigned u3 = (unsigned)f2h(r[6]) | ((unsigned)f2h(r[7]) << 16);
            *(uint4*)(oh + (size_t)i * F_H + 8 * c) = make_uint4(u0, u1, u2, u3);
        } else {
            float* out = (float*)outv;
            float4* op = (float4*)(out + (size_t)i * FOUT + 8 * c);
            op[0] = make_float4(r[0], r[1], r[2], r[3]);
            op[1] = make_float4(r[4], r[5], r[6], r[7]);
        }
    } else {
        float* out = (float*)outv;
        constexpr int VC = FOUT / 8;               // valid lane-chunks (5 for FOUT=40)
        bool act = (c < VC);
        float v[8];
#pragma unroll
        for (int k = 0; k < 8; ++k) {
            float bv = bias[act ? 8 * c + k : 0];
            v[k] = act ? fmaf(acc[k], inv, bv) : -INFINITY;
        }
        float mx = v[0];
#pragma unroll
        for (int k = 1; k < 8; ++k) mx = fmaxf(mx, v[k]);
#pragma unroll
        for (int o = 1; o <= 4; o <<= 1) mx = fmaxf(mx, __shfl_xor(mx, o));  // within 8-lane group
        float es = 0.f;
        if (act) {
#pragma unroll
            for (int k = 0; k < 8; ++k) es += __expf(v[k] - mx);
        }
#pragma unroll
        for (int o = 1; o <= 4; o <<= 1) es += __shfl_xor(es, o);
        if (act) {
            float lse = mx + __logf(es);
            float4* op = (float4*)(out + (size_t)i * FOUT + 8 * c);
            op[0] = make_float4(v[0] - lse, v[1] - lse, v[2] - lse, v[3] - lse);
            op[1] = make_float4(v[4] - lse, v[5] - lse, v[6] - lse, v[7] - lse);
        }
    }
}

// ---------------- launch ----------------

extern "C" void kernel_launch(void* const* d_in, const int* in_sizes, int n_in,
                              void* d_out, int out_size, void* d_ws, size_t ws_size,
                              hipStream_t stream) {
    const float* x   = (const float*)d_in[0];
    const int* edges = (const int*)d_in[1];
    const float* W1  = (const float*)d_in[2];
    const float* av_s1 = (const float*)d_in[3];
    const float* av_d1 = (const float*)d_in[4];
    const float* b1  = (const float*)d_in[5];
    const float* W2  = (const float*)d_in[6];
    const float* av_s2 = (const float*)d_in[7];
    const float* av_d2 = (const float*)d_in[8];
    const float* b2  = (const float*)d_in[9];
    float* out = (float*)d_out;

    const int N  = in_sizes[0] / F_IN;
    const int E  = in_sizes[1] / 2;
    const int Et = E + N;
    const int NB = (N + 255) >> 8;

    char* p = (char*)d_ws;
    auto alloc = [&](size_t bytes) {
        char* q = p;
        p += (bytes + 255) & ~(size_t)255;
        return (void*)q;
    };
    unsigned short* h1 = (unsigned short*)alloc((size_t)N * F_H * 2);  // f16; reused as h2 (padded to 64)
    unsigned short* out1h = (unsigned short*)alloc((size_t)N * F_H * 2);  // f16 agg1 output
    float* as1    = (float*)alloc((size_t)N * 4);
    float* ad1    = (float*)alloc((size_t)N * 4);
    float* as2    = (float*)alloc((size_t)N * 4);
    float* ad2    = (float*)alloc((size_t)N * 4);
    int* rp       = (int*)alloc((size_t)(N + 1) * 4);
    int* perm     = (int*)alloc((size_t)N * 4);
    int* bcnt     = (int*)alloc(NBMAX * 4);
    int* bbase    = (int*)alloc(NBMAX * 4);
    int* bcur     = (int*)alloc(NBMAX * 4);
    int* dcnt     = (int*)alloc(DCLS * 4);
    int* dcur     = (int*)alloc(DCLS * 4);
    unsigned* binned = (unsigned*)alloc((size_t)Et * 4);
    int* csr      = (int*)alloc((size_t)Et * 4);
    unsigned short* WhiT = (unsigned short*)alloc((size_t)F_H * F_IN * 2);
    unsigned short* WloT = (unsigned short*)alloc((size_t)F_H * F_IN * 2);
    (void)n_in; (void)out_size; (void)ws_size;

    const int* srcs = edges;
    const int* dsts = edges + E;

    hipMemsetAsync(bcnt, 0, NBMAX * 4, stream);
    hipMemsetAsync(dcnt, 0, DCLS * 4, stream);

    k_wsplit<<<(F_IN * F_H + 255) / 256, 256, 0, stream>>>(W1, WhiT, WloT);
    k_binA<<<(Et + 2047) / 2048, 256, 0, stream>>>(dsts, bcnt, E, Et, NB);
    k_binB<<<1, NBMAX, 0, stream>>>(bcnt, bbase, bcur, rp, NB, N, Et);
    k_binC<<<(Et + CHUNK - 1) / CHUNK, 256, 0, stream>>>(srcs, dsts, bcur, binned, E, Et, NB);
    k_binD<<<NB, 256, 0, stream>>>(binned, bbase, bcur, rp, csr, N);

    int gN = (N + 255) / 256;
    k_dsortA<<<gN, 256, 0, stream>>>(rp, dcnt, N);
    k_dsortB<<<1, 64, 0, stream>>>(dcnt, dcur);
    k_dsortC<<<gN, 256, 0, stream>>>(rp, dcur, perm, N);

    k_gemm1m<<<(N + 63) / 64, 256, 0, stream>>>(x, WhiT, WloT, av_s1, av_d1, h1, as1, ad1, N);
    int gAgg = (N + 31) / 32;
    k_agg<F_H, true, false, true><<<gAgg, 256, 0, stream>>>(perm, rp, csr, as1, ad1,
                                                            (const uint4*)h1, b1, out1h, N);
    k_gemm2<<<(N + 63) / 64, 256, 0, stream>>>(out1h, W2, av_s2, av_d2, h1, as2, ad2, N);
    k_agg<F_O, false, true, false><<<gAgg, 256, 0, stream>>>(perm, rp, csr, as2, ad2,
                                                             (const uint4*)h1, b2, out, N);
}

// Round 4
// 315.202 us; speedup vs baseline: 1.8607x; 1.8607x over previous
//
#include <hip/hip_runtime.h>
#include <math.h>

// GAT 2-layer, N=100K nodes, E=1.6M edges (+N self loops), fp32 compute,
// f16 feature rows for the edge gather.
// CSR build via 2-level bucket sort (bucket = dst>>8).
// agg: 8 lanes per dst node, 8 nodes per wave, f16 pair-dot (v_dot2_f32_f16),
//   degree-sorted node assignment (perm), quad unroll (4 gathers in flight),
//   agg1 writes f16 out1 rows (stride 64) consumed directly by gemm2.
// gemm1 MFMA: 3-pass truncation-split bf16 (x_hi@W_hi + x_lo@W_hi + x_hi@W_lo).
// FIX r4: k_dsortC was 273us from global-atomic serialization (100K RMWs on
//   ~30 hot addresses). Now two-phase like k_binC: LDS hist -> one global
//   atomicAdd per class per block -> in-block LDS placement.

constexpr int F_IN = 128;
constexpr int F_H  = 64;
constexpr int F_O  = 40;
constexpr int NBMAX = 512;      // max buckets (N <= 131072)
constexpr int CHUNK = 8192;     // edges per block in k_binC
constexpr int DCLS  = 64;       // degree classes for counting sort

using h2 = decltype(__builtin_amdgcn_cvt_pkrtz(0.f, 0.f));   // <2 x half>
typedef __attribute__((ext_vector_type(4))) float f32x4;
typedef __attribute__((ext_vector_type(8))) short s16x8;

__device__ __forceinline__ h2 u2h(unsigned u) { return __builtin_bit_cast(h2, u); }

__device__ __forceinline__ float fdot2f(h2 a, h2 b, float c) {
#if __has_builtin(__builtin_amdgcn_fdot2)
    return __builtin_amdgcn_fdot2(a, b, c, false);      // v_dot2_f32_f16
#else
    return c + (float)a.x * (float)b.x + (float)a.y * (float)b.y;
#endif
}
// interleave two u32s of packed f16 pairs: pklo -> (b.lo16, a.lo16), pkhi -> (b.hi16, a.hi16)
__device__ __forceinline__ h2 pklo(unsigned a, unsigned b) {
    return u2h(__builtin_amdgcn_perm(a, b, 0x05040100u));
}
__device__ __forceinline__ h2 pkhi(unsigned a, unsigned b) {
    return u2h(__builtin_amdgcn_perm(a, b, 0x07060302u));
}
__device__ __forceinline__ unsigned short f2h(float f) {   // RNE f32->f16 bits
    _Float16 x = (_Float16)f;
    return __builtin_bit_cast(unsigned short, x);
}

// ---------------- CSR build: bucket sort ----------------

__global__ __launch_bounds__(256) void k_binA(const int* __restrict__ dsts,
                                              int* __restrict__ bcnt,
                                              int E, int Et, int NB) {
    __shared__ int hist[NBMAX];
    for (int i = threadIdx.x; i < NB; i += 256) hist[i] = 0;
    __syncthreads();
    int e0 = blockIdx.x * 2048;
#pragma unroll
    for (int it = 0; it < 8; ++it) {
        int e = e0 + it * 256 + threadIdx.x;
        if (e < Et) {
            int d = (e < E) ? dsts[e] : (e - E);
            atomicAdd(&hist[d >> 8], 1);
        }
    }
    __syncthreads();
    for (int i = threadIdx.x; i < NB; i += 256) {
        int c = hist[i];
        if (c) atomicAdd(&bcnt[i], c);
    }
}

__global__ __launch_bounds__(NBMAX) void k_binB(const int* __restrict__ bcnt,
                                                int* __restrict__ bbase,
                                                int* __restrict__ bcur,
                                                int* __restrict__ rp,
                                                int NB, int N, int Et) {
    __shared__ int sc[NBMAX];
    int t = threadIdx.x;
    int v = (t < NB) ? bcnt[t] : 0;
    sc[t] = v; __syncthreads();
    int x = v;
    for (int o = 1; o < NBMAX; o <<= 1) {
        int y = (t >= o) ? sc[t - o] : 0;
        __syncthreads();
        x += y;
        sc[t] = x;
        __syncthreads();
    }
    if (t < NB) { int b = x - v; bbase[t] = b; bcur[t] = b; }
    if (t == 0) rp[N] = Et;
}

__global__ __launch_bounds__(256) void k_binC(const int* __restrict__ srcs,
                                              const int* __restrict__ dsts,
                                              int* __restrict__ bcur,
                                              unsigned* __restrict__ binned,
                                              int E, int Et, int NB) {
    __shared__ int hist[NBMAX];
    __shared__ int gbase[NBMAX];
    __shared__ int lcnt[NBMAX];
    int t = threadIdx.x;
    for (int i = t; i < NB; i += 256) hist[i] = 0;
    __syncthreads();
    int e0 = blockIdx.x * CHUNK;
#pragma unroll 4
    for (int it = 0; it < CHUNK / 256; ++it) {
        int e = e0 + it * 256 + t;
        if (e < Et) {
            int d = (e < E) ? dsts[e] : (e - E);
            atomicAdd(&hist[d >> 8], 1);
        }
    }
    __syncthreads();
    for (int i = t; i < NB; i += 256) {
        int c = hist[i];
        gbase[i] = c ? atomicAdd(&bcur[i], c) : 0;
        lcnt[i] = 0;
    }
    __syncthreads();
#pragma unroll 4
    for (int it = 0; it < CHUNK / 256; ++it) {
        int e = e0 + it * 256 + t;
        if (e < Et) {
            int s, d;
            if (e < E) { s = srcs[e]; d = dsts[e]; } else { s = e - E; d = s; }
            int b = d >> 8;
            int p = atomicAdd(&lcnt[b], 1);
            binned[gbase[b] + p] = (unsigned)s | ((unsigned)(d & 255) << 24);
        }
    }
}

__global__ __launch_bounds__(256) void k_binD(const unsigned* __restrict__ binned,
                                              const int* __restrict__ bbase,
                                              const int* __restrict__ bcur,
                                              int* __restrict__ rp,
                                              int* __restrict__ csr, int N) {
    __shared__ int hist[256];
    __shared__ int sc[256];
    __shared__ int lcnt[256];
    int b = blockIdx.x, t = threadIdx.x;
    int base = bbase[b], end = bcur[b];
    hist[t] = 0; __syncthreads();
    for (int j = base + t; j < end; j += 256)
        atomicAdd(&hist[binned[j] >> 24], 1);
    __syncthreads();
    int v = hist[t];
    sc[t] = v; __syncthreads();
    int x = v;
    for (int o = 1; o < 256; o <<= 1) {
        int y = (t >= o) ? sc[t - o] : 0;
        __syncthreads();
        x += y;
        sc[t] = x;
        __syncthreads();
    }
    int pref = x - v;
    int g = (b << 8) + t;
    if (g < N) rp[g] = base + pref;
    sc[t] = pref;
    lcnt[t] = 0;
    __syncthreads();
    for (int j = base + t; j < end; j += 256) {
        unsigned w = binned[j];
        int v2 = (int)(w >> 24);
        int s = (int)(w & 0xFFFFFFu);
        int p = atomicAdd(&lcnt[v2], 1);
        csr[base + sc[v2] + p] = s;
    }
}

// ---------------- degree counting sort -> perm ----------------

__global__ __launch_bounds__(256) void k_dsortA(const int* __restrict__ rp,
                                                int* __restrict__ dcnt, int N) {
    __shared__ int h[DCLS];
    if (threadIdx.x < DCLS) h[threadIdx.x] = 0;
    __syncthreads();
    int i = blockIdx.x * 256 + threadIdx.x;
    if (i < N) {
        int d = min(rp[i + 1] - rp[i], DCLS - 1);
        atomicAdd(&h[d], 1);
    }
    __syncthreads();
    if (threadIdx.x < DCLS) {
        int c = h[threadIdx.x];
        if (c) atomicAdd(&dcnt[threadIdx.x], c);
    }
}

__global__ __launch_bounds__(64) void k_dsortB(const int* __restrict__ dcnt,
                                               int* __restrict__ dcur) {
    int t = threadIdx.x;
    int v = dcnt[t];
    int x = v;
#pragma unroll
    for (int o = 1; o < 64; o <<= 1) {
        int y = __shfl_up(x, o);
        if (t >= o) x += y;
    }
    dcur[t] = x - v;                               // exclusive base
}

// two-phase scatter: LDS hist -> one global atomic per class per block ->
// in-block LDS placement. (The old 1-atomic-per-node version serialized on
// ~30 hot global addresses and cost 273us.)
__global__ __launch_bounds__(256) void k_dsortC(const int* __restrict__ rp,
                                                int* __restrict__ dcur,
                                                int* __restrict__ perm, int N) {
    __shared__ int hist[DCLS];
    __shared__ int gbase[DCLS];
    __shared__ int lcnt[DCLS];
    int t = threadIdx.x;
    if (t < DCLS) hist[t] = 0;
    __syncthreads();
    int i = blockIdx.x * 256 + t;
    int d = -1;
    if (i < N) {
        d = min(rp[i + 1] - rp[i], DCLS - 1);
        atomicAdd(&hist[d], 1);
    }
    __syncthreads();
    if (t < DCLS) {
        int c = hist[t];
        gbase[t] = c ? atomicAdd(&dcur[t], c) : 0;
        lcnt[t] = 0;
    }
    __syncthreads();
    if (i < N) {
        int p = atomicAdd(&lcnt[d], 1);
        perm[gbase[d] + p] = i;
    }
}

// ---------------- W1 split: fp32 [128][64] -> bf16-hi/lo transposed [64][128] ----------------

__global__ __launch_bounds__(256) void k_wsplit(const float* __restrict__ W,
                                                unsigned short* __restrict__ WhiT,
                                                unsigned short* __restrict__ WloT) {
    int i = blockIdx.x * 256 + threadIdx.x;
    if (i >= F_IN * F_H) return;
    int k = i >> 6, c = i & 63;                    // W[k][c], C = F_H = 64
    float w = W[i];
    unsigned u = __float_as_uint(w);
    unsigned hi = u & 0xFFFF0000u;                 // truncation split: residual
    float d = w - __uint_as_float(hi);             // captured exactly by lo
    WhiT[c * F_IN + k] = (unsigned short)(hi >> 16);
    WloT[c * F_IN + k] = (unsigned short)(__float_as_uint(d) >> 16);
}

// ---------------- GEMM1 (MFMA): h1 = f16(x @ W1), fused fp32 alphas ----------------

__global__ __launch_bounds__(256) void k_gemm1m(const float* __restrict__ x,
                                                const unsigned short* __restrict__ WhiT,
                                                const unsigned short* __restrict__ WloT,
                                                const float* __restrict__ avs,
                                                const float* __restrict__ avd,
                                                unsigned short* __restrict__ h,
                                                float* __restrict__ as,
                                                float* __restrict__ ad, int N) {
    __shared__ unsigned short hs[64][72];          // 72: bank-stagger, 16B-aligned rows
    const int t = threadIdx.x;
    const int wv = t >> 6;
    const int lane = t & 63;
    const int lrow = lane & 15;
    const int lk8 = lane >> 4;
    const int r0 = blockIdx.x * 64;
    const int arow = r0 + wv * 16 + lrow;
    const float* xp = x + (size_t)min(arow, N - 1) * F_IN;

    // preload full row slice (8 float4), then split to bf16 hi/lo A-frags
    float4 xv0[4], xv1[4];
#pragma unroll
    for (int kt = 0; kt < 4; ++kt) {
        xv0[kt] = *(const float4*)&xp[kt * 32 + lk8 * 8];
        xv1[kt] = *(const float4*)&xp[kt * 32 + lk8 * 8 + 4];
    }
    s16x8 ah[4], al[4];
#pragma unroll
    for (int kt = 0; kt < 4; ++kt) {
        float e0[8] = {xv0[kt].x, xv0[kt].y, xv0[kt].z, xv0[kt].w,
                       xv1[kt].x, xv1[kt].y, xv1[kt].z, xv1[kt].w};
        unsigned uh[4], ul[4];
#pragma unroll
        for (int p = 0; p < 4; ++p) {
            float a0 = e0[2 * p], a1 = e0[2 * p + 1];
            unsigned u0 = __float_as_uint(a0), u1 = __float_as_uint(a1);
            float d0 = a0 - __uint_as_float(u0 & 0xFFFF0000u);
            float d1 = a1 - __uint_as_float(u1 & 0xFFFF0000u);
            uh[p] = __builtin_amdgcn_perm(u1, u0, 0x07060302u);
            ul[p] = __builtin_amdgcn_perm(__float_as_uint(d1), __float_as_uint(d0), 0x07060302u);
        }
        ah[kt] = __builtin_bit_cast(s16x8, make_uint4(uh[0], uh[1], uh[2], uh[3]));
        al[kt] = __builtin_bit_cast(s16x8, make_uint4(ul[0], ul[1], ul[2], ul[3]));
    }

    f32x4 acc[4] = {};                             // one 16x16 C-tile per ct
#pragma unroll
    for (int kt = 0; kt < 4; ++kt) {
#pragma unroll
        for (int ct = 0; ct < 4; ++ct) {
            const int boff = (ct * 16 + lrow) * F_IN + kt * 32 + lk8 * 8;
            s16x8 bh = *(const s16x8*)&WhiT[boff];
            s16x8 bl = *(const s16x8*)&WloT[boff];
            acc[ct] = __builtin_amdgcn_mfma_f32_16x16x32_bf16(ah[kt], bh, acc[ct], 0, 0, 0);
            acc[ct] = __builtin_amdgcn_mfma_f32_16x16x32_bf16(al[kt], bh, acc[ct], 0, 0, 0);
            acc[ct] = __builtin_amdgcn_mfma_f32_16x16x32_bf16(ah[kt], bl, acc[ct], 0, 0, 0);
        }
    }

    // fused alphas from fp32 accumulators: reduce over 16 cols (lrow groups)
    float avs_c[4], avd_c[4];
#pragma unroll
    for (int ct = 0; ct < 4; ++ct) {
        avs_c[ct] = avs[ct * 16 + lrow];
        avd_c[ct] = avd[ct * 16 + lrow];
    }
#pragma unroll
    for (int r = 0; r < 4; ++r) {
        float ps = acc[0][r] * avs_c[0] + acc[1][r] * avs_c[1]
                 + acc[2][r] * avs_c[2] + acc[3][r] * avs_c[3];
        float pd = acc[0][r] * avd_c[0] + acc[1][r] * avd_c[1]
                 + acc[2][r] * avd_c[2] + acc[3][r] * avd_c[3];
#pragma unroll
        for (int o = 8; o; o >>= 1) {
            ps += __shfl_xor(ps, o, 16);
            pd += __shfl_xor(pd, o, 16);
        }
        int orow = r0 + wv * 16 + lk8 * 4 + r;
        if (lrow == 0 && orow < N) { as[orow] = ps; ad[orow] = pd; }
    }

    // C -> LDS (f16) -> coalesced global store
#pragma unroll
    for (int ct = 0; ct < 4; ++ct)
#pragma unroll
        for (int r = 0; r < 4; ++r)
            hs[wv * 16 + lk8 * 4 + r][ct * 16 + lrow] = f2h(acc[ct][r]);
    __syncthreads();
    const int row = t >> 2, ch = t & 3;
    const int grow = r0 + row;
    if (grow < N) {
        uint4 v0 = *(const uint4*)&hs[row][ch * 16];
        uint4 v1 = *(const uint4*)&hs[row][ch * 16 + 8];
        uint4* gp = (uint4*)(h + (size_t)grow * F_H + ch * 16);
        gp[0] = v0; gp[1] = v1;
    }
}

// ---------------- GEMM2: h2 = f16(out1_f16 @ W2) padded to 64 cols ----------------

__global__ __launch_bounds__(256) void k_gemm2(const unsigned short* __restrict__ xin,
                                               const float* __restrict__ W,
                                               const float* __restrict__ avs,
                                               const float* __restrict__ avd,
                                               unsigned short* __restrict__ h,
                                               float* __restrict__ as,
                                               float* __restrict__ ad, int N) {
    __shared__ __align__(16) float Ws[F_H * F_O];
    for (int i = threadIdx.x; i < F_H * F_O; i += 256) Ws[i] = W[i];
    __syncthreads();
    int t = threadIdx.x;
    int r0 = blockIdx.x * 64 + (t >> 3) * 2;
    int l = t & 7;
    if (r0 >= N) return;
    const uint2* xa = (const uint2*)(xin + (size_t)r0 * F_H);
    const uint2* xb = (const uint2*)(xin + (size_t)(r0 + 1) * F_H);
    float acca[5] = {}, accb[5] = {};
#pragma unroll
    for (int k4 = 0; k4 < F_H / 4; ++k4) {
        uint2 ua = xa[k4];
        uint2 ub = xb[k4];
        h2 a01 = u2h(ua.x), a23 = u2h(ua.y);
        h2 b01 = u2h(ub.x), b23 = u2h(ub.y);
        float xva[4] = {(float)a01.x, (float)a01.y, (float)a23.x, (float)a23.y};
        float xvb[4] = {(float)b01.x, (float)b01.y, (float)b23.x, (float)b23.y};
        int kb = k4 * 4;
#pragma unroll
        for (int kk = 0; kk < 4; ++kk) {
            const float* wr = &Ws[(kb + kk) * F_O + l];
            float w0 = wr[0], w1 = wr[8], w2 = wr[16], w3 = wr[24], w4 = wr[32];
            float xs = xva[kk];
            acca[0] += xs * w0; acca[1] += xs * w1; acca[2] += xs * w2;
            acca[3] += xs * w3; acca[4] += xs * w4;
            float ys = xvb[kk];
            accb[0] += ys * w0; accb[1] += ys * w1; accb[2] += ys * w2;
            accb[3] += ys * w3; accb[4] += ys * w4;
        }
    }
    float psa = 0.f, pda = 0.f, psb = 0.f, pdb = 0.f;
    unsigned short* ra = h + (size_t)r0 * F_H;     // padded row stride 64
    unsigned short* rb = h + (size_t)(r0 + 1) * F_H;
#pragma unroll
    for (int cc = 0; cc < 5; ++cc) {
        int c = l + 8 * cc;
        ra[c] = f2h(acca[cc]);
        rb[c] = f2h(accb[cc]);
        float vs = avs[c], vd = avd[c];
        psa += acca[cc] * vs; pda += acca[cc] * vd;
        psb += accb[cc] * vs; pdb += accb[cc] * vd;
    }
#pragma unroll
    for (int pp = 0; pp < 3; ++pp) {               // zero pad cols 40..63
        int c = 40 + l * 3 + pp;
        ra[c] = 0; rb[c] = 0;
    }
#pragma unroll
    for (int o = 4; o; o >>= 1) {
        psa += __shfl_xor(psa, o, 8);
        pda += __shfl_xor(pda, o, 8);
        psb += __shfl_xor(psb, o, 8);
        pdb += __shfl_xor(pdb, o, 8);
    }
    if (l == 0) { as[r0] = psa; ad[r0] = pda; as[r0 + 1] = psb; ad[r0 + 1] = pdb; }
}

// ---------------- Aggregation: 8 lanes per dst node, 8 nodes per wave ----------------
// Degree-sorted perm -> uniform trip counts within a wave. Quad unroll:
// pad edge list to x4 (w=0), 4 gathers in flight per iteration, 2 acc chains.

template <int FOUT, bool RELU, bool LOGSM, bool F16OUT>
__global__ __launch_bounds__(256) void k_agg(const int* __restrict__ perm,
                                             const int* __restrict__ rp,
                                             const int* __restrict__ csr,
                                             const float* __restrict__ as,
                                             const float* __restrict__ ad,
                                             const uint4* __restrict__ h4,
                                             const float* __restrict__ bias,
                                             void* __restrict__ outv, int N) {
    constexpr int CAP = 64;                        // LDS-resident edges per node
    __shared__ __align__(16) uint2 wsb[4][8][CAP + 2];
    const int w = threadIdx.x >> 6;
    const int g = (threadIdx.x >> 3) & 7;
    const int c = threadIdx.x & 7;
    const int slot = blockIdx.x * 32 + (threadIdx.x >> 3);
    if (slot >= N) return;
    const int i = perm[slot];
    const int start = rp[i], end = rp[i + 1];
    const int deg = end - start;
    const int dm = min(deg, CAP);
    const int dmR4 = (dm + 3) & ~3;                // padded to x4 (<= CAP)
    const float adi = ad[i];

    // Phase A: compute edge weights into this group's LDS segment
    for (int idx = c; idx < dm; idx += 8) {
        int srcn = csr[start + idx];
        float e = as[srcn] + adi;
        e = fmaxf(e, 0.2f * e);                    // leaky_relu
        wsb[w][g][idx] = make_uint2(__float_as_uint(__expf(e)), (unsigned)srcn);
    }
    {   // pad (at most 3 entries): w=0, src=self
        int idx = dm + c;
        if (idx < dmR4) wsb[w][g][idx] = make_uint2(0u, (unsigned)i);
    }

    // Phase B: quad loop (same-wave LDS, no barrier needed)
    const uint4* pw = (const uint4*)wsb[w][g];
    float acc[8] = {}, acc2[8] = {};
    float sacc = 0.f;
    const int nquad = dmR4 >> 2;
    for (int q = 0; q < nquad; ++q) {
        uint4 t0 = pw[2 * q];                      // (w0,s0,w1,s1)
        uint4 t1 = pw[2 * q + 1];                  // (w2,s2,w3,s3)
        uint4 hv0 = h4[((unsigned)t0.y << 3) + c];
        uint4 hv1 = h4[((unsigned)t0.w << 3) + c];
        uint4 hv2 = h4[((unsigned)t1.y << 3) + c];
        uint4 hv3 = h4[((unsigned)t1.w << 3) + c];
        float w0 = __uint_as_float(t0.x), w1 = __uint_as_float(t0.z);
        float w2 = __uint_as_float(t1.x), w3 = __uint_as_float(t1.z);
        sacc += (w0 + w1) + (w2 + w3);
        h2 wp0 = __builtin_amdgcn_cvt_pkrtz(w0, w1);
        h2 wp1 = __builtin_amdgcn_cvt_pkrtz(w2, w3);
        acc[0] = fdot2f(wp0, pklo(hv1.x, hv0.x), acc[0]);
        acc[1] = fdot2f(wp0, pkhi(hv1.x, hv0.x), acc[1]);
        acc[2] = fdot2f(wp0, pklo(hv1.y, hv0.y), acc[2]);
        acc[3] = fdot2f(wp0, pkhi(hv1.y, hv0.y), acc[3]);
        acc[4] = fdot2f(wp0, pklo(hv1.z, hv0.z), acc[4]);
        acc[5] = fdot2f(wp0, pkhi(hv1.z, hv0.z), acc[5]);
        acc[6] = fdot2f(wp0, pklo(hv1.w, hv0.w), acc[6]);
        acc[7] = fdot2f(wp0, pkhi(hv1.w, hv0.w), acc[7]);
        acc2[0] = fdot2f(wp1, pklo(hv3.x, hv2.x), acc2[0]);
        acc2[1] = fdot2f(wp1, pkhi(hv3.x, hv2.x), acc2[1]);
        acc2[2] = fdot2f(wp1, pklo(hv3.y, hv2.y), acc2[2]);
        acc2[3] = fdot2f(wp1, pkhi(hv3.y, hv2.y), acc2[3]);
        acc2[4] = fdot2f(wp1, pklo(hv3.z, hv2.z), acc2[4]);
        acc2[5] = fdot2f(wp1, pkhi(hv3.z, hv2.z), acc2[5]);
        acc2[6] = fdot2f(wp1, pklo(hv3.w, hv2.w), acc2[6]);
        acc2[7] = fdot2f(wp1, pkhi(hv3.w, hv2.w), acc2[7]);
    }

    // rare overflow tail (deg > CAP): single-edge, dup-pair trick with (w,0)
    for (int j = start + dm; j < end; ++j) {
        int srcn = csr[j];
        float e = as[srcn] + adi;
        e = fmaxf(e, 0.2f * e);
        float wv = __expf(e);
        sacc += wv;
        uint4 hv = h4[((unsigned)srcn << 3) + c];
        h2 wp = __builtin_amdgcn_cvt_pkrtz(wv, 0.f);
        acc[0] = fdot2f(wp, pklo(hv.x, hv.x), acc[0]);
        acc[1] = fdot2f(wp, pkhi(hv.x, hv.x), acc[1]);
        acc[2] = fdot2f(wp, pklo(hv.y, hv.y), acc[2]);
        acc[3] = fdot2f(wp, pkhi(hv.y, hv.y), acc[3]);
        acc[4] = fdot2f(wp, pklo(hv.z, hv.z), acc[4]);
        acc[5] = fdot2f(wp, pkhi(hv.z, hv.z), acc[5]);
        acc[6] = fdot2f(wp, pklo(hv.w, hv.w), acc[6]);
        acc[7] = fdot2f(wp, pkhi(hv.w, hv.w), acc[7]);
    }

#pragma unroll
    for (int k = 0; k < 8; ++k) acc[k] += acc2[k];
    float inv = 1.f / sacc;                        // identical across the group

    if (!LOGSM) {
        float r[8];
#pragma unroll
        for (int k = 0; k < 8; ++k) {
            r[k] = fmaf(acc[k], inv, bias[8 * c + k]);
            if (RELU) r[k] = fmaxf(r[k], 0.f);
        }
        if (F16OUT) {                              // f16 rows, stride 64 (= F_H)
            unsigned short* oh = (unsigned short*)outv;
            unsigned u0 = (unsigned)f2h(r[0]) | ((unsigned)f2h(r[1]) << 16);
            unsigned u1 = (unsigned)f2h(r[2]) | ((unsigned)f2h(r[3]) << 16);
            unsigned u2 = (unsigned)f2h(r[4]) | ((unsigned)f2h(r[5]) << 16);
            unsigned u3 = (unsigned)f2h(r[6]) | ((unsigned)f2h(r[7]) << 16);
            *(uint4*)(oh + (size_t)i * F_H + 8 * c) = make_uint4(u0, u1, u2, u3);
        } else {
            float* out = (float*)outv;
            float4* op = (float4*)(out + (size_t)i * FOUT + 8 * c);
            op[0] = make_float4(r[0], r[1], r[2], r[3]);
            op[1] = make_float4(r[4], r[5], r[6], r[7]);
        }
    } else {
        float* out = (float*)outv;
        constexpr int VC = FOUT / 8;               // valid lane-chunks (5 for FOUT=40)
        bool act = (c < VC);
        float v[8];
#pragma unroll
        for (int k = 0; k < 8; ++k) {
            float bv = bias[act ? 8 * c + k : 0];
            v[k] = act ? fmaf(acc[k], inv, bv) : -INFINITY;
        }
        float mx = v[0];
#pragma unroll
        for (int k = 1; k < 8; ++k) mx = fmaxf(mx, v[k]);
#pragma unroll
        for (int o = 1; o <= 4; o <<= 1) mx = fmaxf(mx, __shfl_xor(mx, o));  // within 8-lane group
        float es = 0.f;
        if (act) {
#pragma unroll
            for (int k = 0; k < 8; ++k) es += __expf(v[k] - mx);
        }
#pragma unroll
        for (int o = 1; o <= 4; o <<= 1) es += __shfl_xor(es, o);
        if (act) {
            float lse = mx + __logf(es);
            float4* op = (float4*)(out + (size_t)i * FOUT + 8 * c);
            op[0] = make_float4(v[0] - lse, v[1] - lse, v[2] - lse, v[3] - lse);
            op[1] = make_float4(v[4] - lse, v[5] - lse, v[6] - lse, v[7] - lse);
        }
    }
}

// ---------------- launch ----------------

extern "C" void kernel_launch(void* const* d_in, const int* in_sizes, int n_in,
                              void* d_out, int out_size, void* d_ws, size_t ws_size,
                              hipStream_t stream) {
    const float* x   = (const float*)d_in[0];
    const int* edges = (const int*)d_in[1];
    const float* W1  = (const float*)d_in[2];
    const float* av_s1 = (const float*)d_in[3];
    const float* av_d1 = (const float*)d_in[4];
    const float* b1  = (const float*)d_in[5];
    const float* W2  = (const float*)d_in[6];
    const float* av_s2 = (const float*)d_in[7];
    const float* av_d2 = (const float*)d_in[8];
    const float* b2  = (const float*)d_in[9];
    float* out = (float*)d_out;

    const int N  = in_sizes[0] / F_IN;
    const int E  = in_sizes[1] / 2;
    const int Et = E + N;
    const int NB = (N + 255) >> 8;

    char* p = (char*)d_ws;
    auto alloc = [&](size_t bytes) {
        char* q = p;
        p += (bytes + 255) & ~(size_t)255;
        return (void*)q;
    };
    unsigned short* h1 = (unsigned short*)alloc((size_t)N * F_H * 2);  // f16; reused as h2 (padded to 64)
    unsigned short* out1h = (unsigned short*)alloc((size_t)N * F_H * 2);  // f16 agg1 output
    float* as1    = (float*)alloc((size_t)N * 4);
    float* ad1    = (float*)alloc((size_t)N * 4);
    float* as2    = (float*)alloc((size_t)N * 4);
    float* ad2    = (float*)alloc((size_t)N * 4);
    int* rp       = (int*)alloc((size_t)(N + 1) * 4);
    int* perm     = (int*)alloc((size_t)N * 4);
    int* bcnt     = (int*)alloc(NBMAX * 4);
    int* bbase    = (int*)alloc(NBMAX * 4);
    int* bcur     = (int*)alloc(NBMAX * 4);
    int* dcnt     = (int*)alloc(DCLS * 4);
    int* dcur     = (int*)alloc(DCLS * 4);
    unsigned* binned = (unsigned*)alloc((size_t)Et * 4);
    int* csr      = (int*)alloc((size_t)Et * 4);
    unsigned short* WhiT = (unsigned short*)alloc((size_t)F_H * F_IN * 2);
    unsigned short* WloT = (unsigned short*)alloc((size_t)F_H * F_IN * 2);
    (void)n_in; (void)out_size; (void)ws_size;

    const int* srcs = edges;
    const int* dsts = edges + E;

    hipMemsetAsync(bcnt, 0, NBMAX * 4, stream);
    hipMemsetAsync(dcnt, 0, DCLS * 4, stream);

    k_wsplit<<<(F_IN * F_H + 255) / 256, 256, 0, stream>>>(W1, WhiT, WloT);
    k_binA<<<(Et + 2047) / 2048, 256, 0, stream>>>(dsts, bcnt, E, Et, NB);
    k_binB<<<1, NBMAX, 0, stream>>>(bcnt, bbase, bcur, rp, NB, N, Et);
    k_binC<<<(Et + CHUNK - 1) / CHUNK, 256, 0, stream>>>(srcs, dsts, bcur, binned, E, Et, NB);
    k_binD<<<NB, 256, 0, stream>>>(binned, bbase, bcur, rp, csr, N);

    int gN = (N + 255) / 256;
    k_dsortA<<<gN, 256, 0, stream>>>(rp, dcnt, N);
    k_dsortB<<<1, 64, 0, stream>>>(dcnt, dcur);
    k_dsortC<<<gN, 256, 0, stream>>>(rp, dcur, perm, N);

    k_gemm1m<<<(N + 63) / 64, 256, 0, stream>>>(x, WhiT, WloT, av_s1, av_d1, h1, as1, ad1, N);
    int gAgg = (N + 31) / 32;
    k_agg<F_H, true, false, true><<<gAgg, 256, 0, stream>>>(perm, rp, csr, as1, ad1,
                                                            (const uint4*)h1, b1, out1h, N);
    k_gemm2<<<(N + 63) / 64, 256, 0, stream>>>(out1h, W2, av_s2, av_d2, h1, as2, ad2, N);
    k_agg<F_O, false, true, false><<<gAgg, 256, 0, stream>>>(perm, rp, csr, as2, ad2,
                                                             (const uint4*)h1, b2, out, N);
}

// Round 5
// 296.886 us; speedup vs baseline: 1.9755x; 1.0617x over previous
//
#include <hip/hip_runtime.h>
#include <math.h>

// GAT 2-layer, N=100K nodes, E=1.6M edges (+N self loops), fp32 compute,
// f16 feature rows for the edge gather.
// CSR build via 2-level bucket sort (bucket = dst>>8).
// agg: 8 lanes per dst node, 8 nodes per wave, f16 pair-dot (v_dot2_f32_f16),
//   OCTET unroll: 8 edges/iter -> 8 gathers in flight per lane (latency-bound
//   kernel, counters show both VALU and HBM pipes idle).
//   agg1 writes f16 out1 rows (stride 64) consumed directly by gemm2.
// gemm1 MFMA: 3-pass truncation-split bf16 (x_hi@W_hi + x_lo@W_hi + x_hi@W_lo).
// r5: degree-sort REMOVED (measured: +1.4us on agg, +13MB fetch, straggler
//   tail from sorted block order; divergence theory disproven by counters).

constexpr int F_IN = 128;
constexpr int F_H  = 64;
constexpr int F_O  = 40;
constexpr int NBMAX = 512;      // max buckets (N <= 131072)
constexpr int CHUNK = 8192;     // edges per block in k_binC

using h2 = decltype(__builtin_amdgcn_cvt_pkrtz(0.f, 0.f));   // <2 x half>
typedef __attribute__((ext_vector_type(4))) float f32x4;
typedef __attribute__((ext_vector_type(8))) short s16x8;

__device__ __forceinline__ h2 u2h(unsigned u) { return __builtin_bit_cast(h2, u); }

__device__ __forceinline__ float fdot2f(h2 a, h2 b, float c) {
#if __has_builtin(__builtin_amdgcn_fdot2)
    return __builtin_amdgcn_fdot2(a, b, c, false);      // v_dot2_f32_f16
#else
    return c + (float)a.x * (float)b.x + (float)a.y * (float)b.y;
#endif
}
// interleave two u32s of packed f16 pairs: pklo -> (b.lo16, a.lo16), pkhi -> (b.hi16, a.hi16)
__device__ __forceinline__ h2 pklo(unsigned a, unsigned b) {
    return u2h(__builtin_amdgcn_perm(a, b, 0x05040100u));
}
__device__ __forceinline__ h2 pkhi(unsigned a, unsigned b) {
    return u2h(__builtin_amdgcn_perm(a, b, 0x07060302u));
}
__device__ __forceinline__ unsigned short f2h(float f) {   // RNE f32->f16 bits
    _Float16 x = (_Float16)f;
    return __builtin_bit_cast(unsigned short, x);
}

// ---------------- CSR build: bucket sort ----------------

__global__ __launch_bounds__(256) void k_binA(const int* __restrict__ dsts,
                                              int* __restrict__ bcnt,
                                              int E, int Et, int NB) {
    __shared__ int hist[NBMAX];
    for (int i = threadIdx.x; i < NB; i += 256) hist[i] = 0;
    __syncthreads();
    int e0 = blockIdx.x * 2048;
#pragma unroll
    for (int it = 0; it < 8; ++it) {
        int e = e0 + it * 256 + threadIdx.x;
        if (e < Et) {
            int d = (e < E) ? dsts[e] : (e - E);
            atomicAdd(&hist[d >> 8], 1);
        }
    }
    __syncthreads();
    for (int i = threadIdx.x; i < NB; i += 256) {
        int c = hist[i];
        if (c) atomicAdd(&bcnt[i], c);
    }
}

__global__ __launch_bounds__(NBMAX) void k_binB(const int* __restrict__ bcnt,
                                                int* __restrict__ bbase,
                                                int* __restrict__ bcur,
                                                int* __restrict__ rp,
                                                int NB, int N, int Et) {
    __shared__ int sc[NBMAX];
    int t = threadIdx.x;
    int v = (t < NB) ? bcnt[t] : 0;
    sc[t] = v; __syncthreads();
    int x = v;
    for (int o = 1; o < NBMAX; o <<= 1) {
        int y = (t >= o) ? sc[t - o] : 0;
        __syncthreads();
        x += y;
        sc[t] = x;
        __syncthreads();
    }
    if (t < NB) { int b = x - v; bbase[t] = b; bcur[t] = b; }
    if (t == 0) rp[N] = Et;
}

__global__ __launch_bounds__(256) void k_binC(const int* __restrict__ srcs,
                                              const int* __restrict__ dsts,
                                              int* __restrict__ bcur,
                                              unsigned* __restrict__ binned,
                                              int E, int Et, int NB) {
    __shared__ int hist[NBMAX];
    __shared__ int gbase[NBMAX];
    __shared__ int lcnt[NBMAX];
    int t = threadIdx.x;
    for (int i = t; i < NB; i += 256) hist[i] = 0;
    __syncthreads();
    int e0 = blockIdx.x * CHUNK;
#pragma unroll 4
    for (int it = 0; it < CHUNK / 256; ++it) {
        int e = e0 + it * 256 + t;
        if (e < Et) {
            int d = (e < E) ? dsts[e] : (e - E);
            atomicAdd(&hist[d >> 8], 1);
        }
    }
    __syncthreads();
    for (int i = t; i < NB; i += 256) {
        int c = hist[i];
        gbase[i] = c ? atomicAdd(&bcur[i], c) : 0;
        lcnt[i] = 0;
    }
    __syncthreads();
#pragma unroll 4
    for (int it = 0; it < CHUNK / 256; ++it) {
        int e = e0 + it * 256 + t;
        if (e < Et) {
            int s, d;
            if (e < E) { s = srcs[e]; d = dsts[e]; } else { s = e - E; d = s; }
            int b = d >> 8;
            int p = atomicAdd(&lcnt[b], 1);
            binned[gbase[b] + p] = (unsigned)s | ((unsigned)(d & 255) << 24);
        }
    }
}

__global__ __launch_bounds__(256) void k_binD(const unsigned* __restrict__ binned,
                                              const int* __restrict__ bbase,
                                              const int* __restrict__ bcur,
                                              int* __restrict__ rp,
                                              int* __restrict__ csr, int N) {
    __shared__ int hist[256];
    __shared__ int sc[256];
    __shared__ int lcnt[256];
    int b = blockIdx.x, t = threadIdx.x;
    int base = bbase[b], end = bcur[b];
    hist[t] = 0; __syncthreads();
    for (int j = base + t; j < end; j += 256)
        atomicAdd(&hist[binned[j] >> 24], 1);
    __syncthreads();
    int v = hist[t];
    sc[t] = v; __syncthreads();
    int x = v;
    for (int o = 1; o < 256; o <<= 1) {
        int y = (t >= o) ? sc[t - o] : 0;
        __syncthreads();
        x += y;
        sc[t] = x;
        __syncthreads();
    }
    int pref = x - v;
    int g = (b << 8) + t;
    if (g < N) rp[g] = base + pref;
    sc[t] = pref;
    lcnt[t] = 0;
    __syncthreads();
    for (int j = base + t; j < end; j += 256) {
        unsigned w = binned[j];
        int v2 = (int)(w >> 24);
        int s = (int)(w & 0xFFFFFFu);
        int p = atomicAdd(&lcnt[v2], 1);
        csr[base + sc[v2] + p] = s;
    }
}

// ---------------- W1 split: fp32 [128][64] -> bf16-hi/lo transposed [64][128] ----------------

__global__ __launch_bounds__(256) void k_wsplit(const float* __restrict__ W,
                                                unsigned short* __restrict__ WhiT,
                                                unsigned short* __restrict__ WloT) {
    int i = blockIdx.x * 256 + threadIdx.x;
    if (i >= F_IN * F_H) return;
    int k = i >> 6, c = i & 63;                    // W[k][c], C = F_H = 64
    float w = W[i];
    unsigned u = __float_as_uint(w);
    unsigned hi = u & 0xFFFF0000u;                 // truncation split: residual
    float d = w - __uint_as_float(hi);             // captured exactly by lo
    WhiT[c * F_IN + k] = (unsigned short)(hi >> 16);
    WloT[c * F_IN + k] = (unsigned short)(__float_as_uint(d) >> 16);
}

// ---------------- GEMM1 (MFMA): h1 = f16(x @ W1), fused fp32 alphas ----------------

__global__ __launch_bounds__(256) void k_gemm1m(const float* __restrict__ x,
                                                const unsigned short* __restrict__ WhiT,
                                                const unsigned short* __restrict__ WloT,
                                                const float* __restrict__ avs,
                                                const float* __restrict__ avd,
                                                unsigned short* __restrict__ h,
                                                float* __restrict__ as,
                                                float* __restrict__ ad, int N) {
    __shared__ unsigned short hs[64][72];          // 72: bank-stagger, 16B-aligned rows
    const int t = threadIdx.x;
    const int wv = t >> 6;
    const int lane = t & 63;
    const int lrow = lane & 15;
    const int lk8 = lane >> 4;
    const int r0 = blockIdx.x * 64;
    const int arow = r0 + wv * 16 + lrow;
    const float* xp = x + (size_t)min(arow, N - 1) * F_IN;

    // preload full row slice (8 float4), then split to bf16 hi/lo A-frags
    float4 xv0[4], xv1[4];
#pragma unroll
    for (int kt = 0; kt < 4; ++kt) {
        xv0[kt] = *(const float4*)&xp[kt * 32 + lk8 * 8];
        xv1[kt] = *(const float4*)&xp[kt * 32 + lk8 * 8 + 4];
    }
    s16x8 ah[4], al[4];
#pragma unroll
    for (int kt = 0; kt < 4; ++kt) {
        float e0[8] = {xv0[kt].x, xv0[kt].y, xv0[kt].z, xv0[kt].w,
                       xv1[kt].x, xv1[kt].y, xv1[kt].z, xv1[kt].w};
        unsigned uh[4], ul[4];
#pragma unroll
        for (int p = 0; p < 4; ++p) {
            float a0 = e0[2 * p], a1 = e0[2 * p + 1];
            unsigned u0 = __float_as_uint(a0), u1 = __float_as_uint(a1);
            float d0 = a0 - __uint_as_float(u0 & 0xFFFF0000u);
            float d1 = a1 - __uint_as_float(u1 & 0xFFFF0000u);
            uh[p] = __builtin_amdgcn_perm(u1, u0, 0x07060302u);
            ul[p] = __builtin_amdgcn_perm(__float_as_uint(d1), __float_as_uint(d0), 0x07060302u);
        }
        ah[kt] = __builtin_bit_cast(s16x8, make_uint4(uh[0], uh[1], uh[2], uh[3]));
        al[kt] = __builtin_bit_cast(s16x8, make_uint4(ul[0], ul[1], ul[2], ul[3]));
    }

    f32x4 acc[4] = {};                             // one 16x16 C-tile per ct
#pragma unroll
    for (int kt = 0; kt < 4; ++kt) {
#pragma unroll
        for (int ct = 0; ct < 4; ++ct) {
            const int boff = (ct * 16 + lrow) * F_IN + kt * 32 + lk8 * 8;
            s16x8 bh = *(const s16x8*)&WhiT[boff];
            s16x8 bl = *(const s16x8*)&WloT[boff];
            acc[ct] = __builtin_amdgcn_mfma_f32_16x16x32_bf16(ah[kt], bh, acc[ct], 0, 0, 0);
            acc[ct] = __builtin_amdgcn_mfma_f32_16x16x32_bf16(al[kt], bh, acc[ct], 0, 0, 0);
            acc[ct] = __builtin_amdgcn_mfma_f32_16x16x32_bf16(ah[kt], bl, acc[ct], 0, 0, 0);
        }
    }

    // fused alphas from fp32 accumulators: reduce over 16 cols (lrow groups)
    float avs_c[4], avd_c[4];
#pragma unroll
    for (int ct = 0; ct < 4; ++ct) {
        avs_c[ct] = avs[ct * 16 + lrow];
        avd_c[ct] = avd[ct * 16 + lrow];
    }
#pragma unroll
    for (int r = 0; r < 4; ++r) {
        float ps = acc[0][r] * avs_c[0] + acc[1][r] * avs_c[1]
                 + acc[2][r] * avs_c[2] + acc[3][r] * avs_c[3];
        float pd = acc[0][r] * avd_c[0] + acc[1][r] * avd_c[1]
                 + acc[2][r] * avd_c[2] + acc[3][r] * avd_c[3];
#pragma unroll
        for (int o = 8; o; o >>= 1) {
            ps += __shfl_xor(ps, o, 16);
            pd += __shfl_xor(pd, o, 16);
        }
        int orow = r0 + wv * 16 + lk8 * 4 + r;
        if (lrow == 0 && orow < N) { as[orow] = ps; ad[orow] = pd; }
    }

    // C -> LDS (f16) -> coalesced global store
#pragma unroll
    for (int ct = 0; ct < 4; ++ct)
#pragma unroll
        for (int r = 0; r < 4; ++r)
            hs[wv * 16 + lk8 * 4 + r][ct * 16 + lrow] = f2h(acc[ct][r]);
    __syncthreads();
    const int row = t >> 2, ch = t & 3;
    const int grow = r0 + row;
    if (grow < N) {
        uint4 v0 = *(const uint4*)&hs[row][ch * 16];
        uint4 v1 = *(const uint4*)&hs[row][ch * 16 + 8];
        uint4* gp = (uint4*)(h + (size_t)grow * F_H + ch * 16);
        gp[0] = v0; gp[1] = v1;
    }
}

// ---------------- GEMM2: h2 = f16(out1_f16 @ W2) padded to 64 cols ----------------

__global__ __launch_bounds__(256) void k_gemm2(const unsigned short* __restrict__ xin,
                                               const float* __restrict__ W,
                                               const float* __restrict__ avs,
                                               const float* __restrict__ avd,
                                               unsigned short* __restrict__ h,
                                               float* __restrict__ as,
                                               float* __restrict__ ad, int N) {
    __shared__ __align__(16) float Ws[F_H * F_O];
    for (int i = threadIdx.x; i < F_H * F_O; i += 256) Ws[i] = W[i];
    __syncthreads();
    int t = threadIdx.x;
    int r0 = blockIdx.x * 64 + (t >> 3) * 2;
    int l = t & 7;
    if (r0 >= N) return;
    const uint2* xa = (const uint2*)(xin + (size_t)r0 * F_H);
    const uint2* xb = (const uint2*)(xin + (size_t)(r0 + 1) * F_H);
    float acca[5] = {}, accb[5] = {};
#pragma unroll
    for (int k4 = 0; k4 < F_H / 4; ++k4) {
        uint2 ua = xa[k4];
        uint2 ub = xb[k4];
        h2 a01 = u2h(ua.x), a23 = u2h(ua.y);
        h2 b01 = u2h(ub.x), b23 = u2h(ub.y);
        float xva[4] = {(float)a01.x, (float)a01.y, (float)a23.x, (float)a23.y};
        float xvb[4] = {(float)b01.x, (float)b01.y, (float)b23.x, (float)b23.y};
        int kb = k4 * 4;
#pragma unroll
        for (int kk = 0; kk < 4; ++kk) {
            const float* wr = &Ws[(kb + kk) * F_O + l];
            float w0 = wr[0], w1 = wr[8], w2 = wr[16], w3 = wr[24], w4 = wr[32];
            float xs = xva[kk];
            acca[0] += xs * w0; acca[1] += xs * w1; acca[2] += xs * w2;
            acca[3] += xs * w3; acca[4] += xs * w4;
            float ys = xvb[kk];
            accb[0] += ys * w0; accb[1] += ys * w1; accb[2] += ys * w2;
            accb[3] += ys * w3; accb[4] += ys * w4;
        }
    }
    float psa = 0.f, pda = 0.f, psb = 0.f, pdb = 0.f;
    unsigned short* ra = h + (size_t)r0 * F_H;     // padded row stride 64
    unsigned short* rb = h + (size_t)(r0 + 1) * F_H;
#pragma unroll
    for (int cc = 0; cc < 5; ++cc) {
        int c = l + 8 * cc;
        ra[c] = f2h(acca[cc]);
        rb[c] = f2h(accb[cc]);
        float vs = avs[c], vd = avd[c];
        psa += acca[cc] * vs; pda += acca[cc] * vd;
        psb += accb[cc] * vs; pdb += accb[cc] * vd;
    }
#pragma unroll
    for (int pp = 0; pp < 3; ++pp) {               // zero pad cols 40..63
        int c = 40 + l * 3 + pp;
        ra[c] = 0; rb[c] = 0;
    }
#pragma unroll
    for (int o = 4; o; o >>= 1) {
        psa += __shfl_xor(psa, o, 8);
        pda += __shfl_xor(pda, o, 8);
        psb += __shfl_xor(psb, o, 8);
        pdb += __shfl_xor(pdb, o, 8);
    }
    if (l == 0) { as[r0] = psa; ad[r0] = pda; as[r0 + 1] = psb; ad[r0 + 1] = pdb; }
}

// ---------------- Aggregation: 8 lanes per dst node, 8 nodes per wave ----------------
// Octet loop: edge list padded to x8 (w=0, src=self -> pad gathers are
// L2-hot), 8 independent 16B gathers in flight per lane, 2 acc chains.

template <int FOUT, bool RELU, bool LOGSM, bool F16OUT>
__global__ __launch_bounds__(256) void k_agg(const int* __restrict__ rp,
                                             const int* __restrict__ csr,
                                             const float* __restrict__ as,
                                             const float* __restrict__ ad,
                                             const uint4* __restrict__ h4,
                                             const float* __restrict__ bias,
                                             void* __restrict__ outv, int N) {
    constexpr int CAP = 64;                        // LDS-resident edges per node
    __shared__ __align__(16) uint2 wsb[4][8][CAP + 2];
    const int w = threadIdx.x >> 6;
    const int g = (threadIdx.x >> 3) & 7;
    const int c = threadIdx.x & 7;
    const int i = blockIdx.x * 32 + (threadIdx.x >> 3);
    if (i >= N) return;
    const int start = rp[i], end = rp[i + 1];
    const int deg = end - start;
    const int dm = min(deg, CAP);
    const int dmR8 = (dm + 7) & ~7;                // padded to x8 (<= CAP)
    const float adi = ad[i];

    // Phase A: compute edge weights into this group's LDS segment
    for (int idx = c; idx < dm; idx += 8) {
        int srcn = csr[start + idx];
        float e = as[srcn] + adi;
        e = fmaxf(e, 0.2f * e);                    // leaky_relu
        wsb[w][g][idx] = make_uint2(__float_as_uint(__expf(e)), (unsigned)srcn);
    }
    {   // pad (at most 7 entries): w=0, src=self
        int idx = dm + c;
        if (idx < dmR8) wsb[w][g][idx] = make_uint2(0u, (unsigned)i);
    }

    // Phase B: octet loop (same-wave LDS, no barrier needed)
    const uint4* pw = (const uint4*)wsb[w][g];
    float acc[8] = {}, acc2[8] = {};
    float sacc = 0.f;
    const int noct = dmR8 >> 3;
    for (int q = 0; q < noct; ++q) {
        uint4 m0 = pw[4 * q];                      // (w0,s0,w1,s1)
        uint4 m1 = pw[4 * q + 1];                  // (w2,s2,w3,s3)
        uint4 m2 = pw[4 * q + 2];                  // (w4,s4,w5,s5)
        uint4 m3 = pw[4 * q + 3];                  // (w6,s6,w7,s7)
        uint4 hv0 = h4[((unsigned)m0.y << 3) + c];
        uint4 hv1 = h4[((unsigned)m0.w << 3) + c];
        uint4 hv2 = h4[((unsigned)m1.y << 3) + c];
        uint4 hv3 = h4[((unsigned)m1.w << 3) + c];
        uint4 hv4 = h4[((unsigned)m2.y << 3) + c];
        uint4 hv5 = h4[((unsigned)m2.w << 3) + c];
        uint4 hv6 = h4[((unsigned)m3.y << 3) + c];
        uint4 hv7 = h4[((unsigned)m3.w << 3) + c];
        float w0 = __uint_as_float(m0.x), w1 = __uint_as_float(m0.z);
        float w2 = __uint_as_float(m1.x), w3 = __uint_as_float(m1.z);
        float w4 = __uint_as_float(m2.x), w5 = __uint_as_float(m2.z);
        float w6 = __uint_as_float(m3.x), w7 = __uint_as_float(m3.z);
        sacc += ((w0 + w1) + (w2 + w3)) + ((w4 + w5) + (w6 + w7));
        h2 wp0 = __builtin_amdgcn_cvt_pkrtz(w0, w1);
        h2 wp1 = __builtin_amdgcn_cvt_pkrtz(w2, w3);
        h2 wp2 = __builtin_amdgcn_cvt_pkrtz(w4, w5);
        h2 wp3 = __builtin_amdgcn_cvt_pkrtz(w6, w7);
        acc[0] = fdot2f(wp0, pklo(hv1.x, hv0.x), acc[0]);
        acc[1] = fdot2f(wp0, pkhi(hv1.x, hv0.x), acc[1]);
        acc[2] = fdot2f(wp0, pklo(hv1.y, hv0.y), acc[2]);
        acc[3] = fdot2f(wp0, pkhi(hv1.y, hv0.y), acc[3]);
        acc[4] = fdot2f(wp0, pklo(hv1.z, hv0.z), acc[4]);
        acc[5] = fdot2f(wp0, pkhi(hv1.z, hv0.z), acc[5]);
        acc[6] = fdot2f(wp0, pklo(hv1.w, hv0.w), acc[6]);
        acc[7] = fdot2f(wp0, pkhi(hv1.w, hv0.w), acc[7]);
        acc2[0] = fdot2f(wp1, pklo(hv3.x, hv2.x), acc2[0]);
        acc2[1] = fdot2f(wp1, pkhi(hv3.x, hv2.x), acc2[1]);
        acc2[2] = fdot2f(wp1, pklo(hv3.y, hv2.y), acc2[2]);
        acc2[3] = fdot2f(wp1, pkhi(hv3.y, hv2.y), acc2[3]);
        acc2[4] = fdot2f(wp1, pklo(hv3.z, hv2.z), acc2[4]);
        acc2[5] = fdot2f(wp1, pkhi(hv3.z, hv2.z), acc2[5]);
        acc2[6] = fdot2f(wp1, pklo(hv3.w, hv2.w), acc2[6]);
        acc2[7] = fdot2f(wp1, pkhi(hv3.w, hv2.w), acc2[7]);
        acc[0] = fdot2f(wp2, pklo(hv5.x, hv4.x), acc[0]);
        acc[1] = fdot2f(wp2, pkhi(hv5.x, hv4.x), acc[1]);
        acc[2] = fdot2f(wp2, pklo(hv5.y, hv4.y), acc[2]);
        acc[3] = fdot2f(wp2, pkhi(hv5.y, hv4.y), acc[3]);
        acc[4] = fdot2f(wp2, pklo(hv5.z, hv4.z), acc[4]);
        acc[5] = fdot2f(wp2, pkhi(hv5.z, hv4.z), acc[5]);
        acc[6] = fdot2f(wp2, pklo(hv5.w, hv4.w), acc[6]);
        acc[7] = fdot2f(wp2, pkhi(hv5.w, hv4.w), acc[7]);
        acc2[0] = fdot2f(wp3, pklo(hv7.x, hv6.x), acc2[0]);
        acc2[1] = fdot2f(wp3, pkhi(hv7.x, hv6.x), acc2[1]);
        acc2[2] = fdot2f(wp3, pklo(hv7.y, hv6.y), acc2[2]);
        acc2[3] = fdot2f(wp3, pkhi(hv7.y, hv6.y), acc2[3]);
        acc2[4] = fdot2f(wp3, pklo(hv7.z, hv6.z), acc2[4]);
        acc2[5] = fdot2f(wp3, pkhi(hv7.z, hv6.z), acc2[5]);
        acc2[6] = fdot2f(wp3, pklo(hv7.w, hv6.w), acc2[6]);
        acc2[7] = fdot2f(wp3, pkhi(hv7.w, hv6.w), acc2[7]);
    }

    // rare overflow tail (deg > CAP): single-edge, dup-pair trick with (w,0)
    for (int j = start + dm; j < end; ++j) {
        int srcn = csr[j];
        float e = as[srcn] + adi;
        e = fmaxf(e, 0.2f * e);
        float wv = __expf(e);
        sacc += wv;
        uint4 hv = h4[((unsigned)srcn << 3) + c];
        h2 wp = __builtin_amdgcn_cvt_pkrtz(wv, 0.f);
        acc[0] = fdot2f(wp, pklo(hv.x, hv.x), acc[0]);
        acc[1] = fdot2f(wp, pkhi(hv.x, hv.x), acc[1]);
        acc[2] = fdot2f(wp, pklo(hv.y, hv.y), acc[2]);
        acc[3] = fdot2f(wp, pkhi(hv.y, hv.y), acc[3]);
        acc[4] = fdot2f(wp, pklo(hv.z, hv.z), acc[4]);
        acc[5] = fdot2f(wp, pkhi(hv.z, hv.z), acc[5]);
        acc[6] = fdot2f(wp, pklo(hv.w, hv.w), acc[6]);
        acc[7] = fdot2f(wp, pkhi(hv.w, hv.w), acc[7]);
    }

#pragma unroll
    for (int k = 0; k < 8; ++k) acc[k] += acc2[k];
    float inv = 1.f / sacc;                        // identical across the group

    if (!LOGSM) {
        float r[8];
#pragma unroll
        for (int k = 0; k < 8; ++k) {
            r[k] = fmaf(acc[k], inv, bias[8 * c + k]);
            if (RELU) r[k] = fmaxf(r[k], 0.f);
        }
        if (F16OUT) {                              // f16 rows, stride 64 (= F_H)
            unsigned short* oh = (unsigned short*)outv;
            unsigned u0 = (unsigned)f2h(r[0]) | ((unsigned)f2h(r[1]) << 16);
            unsigned u1 = (unsigned)f2h(r[2]) | ((unsigned)f2h(r[3]) << 16);
            unsigned u2 = (unsigned)f2h(r[4]) | ((unsigned)f2h(r[5]) << 16);
            unsigned u3 = (unsigned)f2h(r[6]) | ((unsigned)f2h(r[7]) << 16);
            *(uint4*)(oh + (size_t)i * F_H + 8 * c) = make_uint4(u0, u1, u2, u3);
        } else {
            float* out = (float*)outv;
            float4* op = (float4*)(out + (size_t)i * FOUT + 8 * c);
            op[0] = make_float4(r[0], r[1], r[2], r[3]);
            op[1] = make_float4(r[4], r[5], r[6], r[7]);
        }
    } else {
        float* out = (float*)outv;
        constexpr int VC = FOUT / 8;               // valid lane-chunks (5 for FOUT=40)
        bool act = (c < VC);
        float v[8];
#pragma unroll
        for (int k = 0; k < 8; ++k) {
            float bv = bias[act ? 8 * c + k : 0];
            v[k] = act ? fmaf(acc[k], inv, bv) : -INFINITY;
        }
        float mx = v[0];
#pragma unroll
        for (int k = 1; k < 8; ++k) mx = fmaxf(mx, v[k]);
#pragma unroll
        for (int o = 1; o <= 4; o <<= 1) mx = fmaxf(mx, __shfl_xor(mx, o));  // within 8-lane group
        float es = 0.f;
        if (act) {
#pragma unroll
            for (int k = 0; k < 8; ++k) es += __expf(v[k] - mx);
        }
#pragma unroll
        for (int o = 1; o <= 4; o <<= 1) es += __shfl_xor(es, o);
        if (act) {
            float lse = mx + __logf(es);
            float4* op = (float4*)(out + (size_t)i * FOUT + 8 * c);
            op[0] = make_float4(v[0] - lse, v[1] - lse, v[2] - lse, v[3] - lse);
            op[1] = make_float4(v[4] - lse, v[5] - lse, v[6] - lse, v[7] - lse);
        }
    }
}

// ---------------- launch ----------------

extern "C" void kernel_launch(void* const* d_in, const int* in_sizes, int n_in,
                              void* d_out, int out_size, void* d_ws, size_t ws_size,
                              hipStream_t stream) {
    const float* x   = (const float*)d_in[0];
    const int* edges = (const int*)d_in[1];
    const float* W1  = (const float*)d_in[2];
    const float* av_s1 = (const float*)d_in[3];
    const float* av_d1 = (const float*)d_in[4];
    const float* b1  = (const float*)d_in[5];
    const float* W2  = (const float*)d_in[6];
    const float* av_s2 = (const float*)d_in[7];
    const float* av_d2 = (const float*)d_in[8];
    const float* b2  = (const float*)d_in[9];
    float* out = (float*)d_out;

    const int N  = in_sizes[0] / F_IN;
    const int E  = in_sizes[1] / 2;
    const int Et = E + N;
    const int NB = (N + 255) >> 8;

    char* p = (char*)d_ws;
    auto alloc = [&](size_t bytes) {
        char* q = p;
        p += (bytes + 255) & ~(size_t)255;
        return (void*)q;
    };
    unsigned short* h1 = (unsigned short*)alloc((size_t)N * F_H * 2);  // f16; reused as h2 (padded to 64)
    unsigned short* out1h = (unsigned short*)alloc((size_t)N * F_H * 2);  // f16 agg1 output
    float* as1    = (float*)alloc((size_t)N * 4);
    float* ad1    = (float*)alloc((size_t)N * 4);
    float* as2    = (float*)alloc((size_t)N * 4);
    float* ad2    = (float*)alloc((size_t)N * 4);
    int* rp       = (int*)alloc((size_t)(N + 1) * 4);
    int* bcnt     = (int*)alloc(NBMAX * 4);
    int* bbase    = (int*)alloc(NBMAX * 4);
    int* bcur     = (int*)alloc(NBMAX * 4);
    unsigned* binned = (unsigned*)alloc((size_t)Et * 4);
    int* csr      = (int*)alloc((size_t)Et * 4);
    unsigned short* WhiT = (unsigned short*)alloc((size_t)F_H * F_IN * 2);
    unsigned short* WloT = (unsigned short*)alloc((size_t)F_H * F_IN * 2);
    (void)n_in; (void)out_size; (void)ws_size;

    const int* srcs = edges;
    const int* dsts = edges + E;

    hipMemsetAsync(bcnt, 0, NBMAX * 4, stream);

    k_wsplit<<<(F_IN * F_H + 255) / 256, 256, 0, stream>>>(W1, WhiT, WloT);
    k_binA<<<(Et + 2047) / 2048, 256, 0, stream>>>(dsts, bcnt, E, Et, NB);
    k_binB<<<1, NBMAX, 0, stream>>>(bcnt, bbase, bcur, rp, NB, N, Et);
    k_binC<<<(Et + CHUNK - 1) / CHUNK, 256, 0, stream>>>(srcs, dsts, bcur, binned, E, Et, NB);
    k_binD<<<NB, 256, 0, stream>>>(binned, bbase, bcur, rp, csr, N);

    k_gemm1m<<<(N + 63) / 64, 256, 0, stream>>>(x, WhiT, WloT, av_s1, av_d1, h1, as1, ad1, N);
    int gAgg = (N + 31) / 32;
    k_agg<F_H, true, false, true><<<gAgg, 256, 0, stream>>>(rp, csr, as1, ad1,
                                                            (const uint4*)h1, b1, out1h, N);
    k_gemm2<<<(N + 63) / 64, 256, 0, stream>>>(out1h, W2, av_s2, av_d2, h1, as2, ad2, N);
    k_agg<F_O, false, true, false><<<gAgg, 256, 0, stream>>>(rp, csr, as2, ad2,
                                                             (const uint4*)h1, b2, out, N);
}

// Round 6
// 291.888 us; speedup vs baseline: 2.0094x; 1.0171x over previous
//
#include <hip/hip_runtime.h>
#include <math.h>

// GAT 2-layer, N=100K nodes, E=1.6M edges (+N self loops), fp32 compute,
// f16 feature rows for the edge gather.
// CSR build via 2-level bucket sort (bucket = dst>>8).
// agg: 8 lanes per dst node, 8 nodes per wave, f16 pair-dot (v_dot2_f32_f16),
//   octet unroll. Layer-2 h rows COMPACT 80B (ROWB=5 uint4) -> 37% less
//   gather volume (agg is L2-fill-rate bound: 12.8MB table vs 4MB/XCD L2).
// gemm1 MFMA 3-pass truncation-split bf16; r6: x staged through LDS with
//   fully-coalesced loads (was: direct-to-frag global gather, lane stride
//   512B -> latency-bound at 28% occupancy, 41us with all pipes <7%).

constexpr int F_IN = 128;
constexpr int F_H  = 64;
constexpr int F_O  = 40;
constexpr int NBMAX = 512;      // max buckets (N <= 131072)
constexpr int CHUNK = 8192;     // edges per block in k_binC

using h2 = decltype(__builtin_amdgcn_cvt_pkrtz(0.f, 0.f));   // <2 x half>
typedef __attribute__((ext_vector_type(4))) float f32x4;
typedef __attribute__((ext_vector_type(8))) short s16x8;

__device__ __forceinline__ h2 u2h(unsigned u) { return __builtin_bit_cast(h2, u); }

__device__ __forceinline__ float fdot2f(h2 a, h2 b, float c) {
#if __has_builtin(__builtin_amdgcn_fdot2)
    return __builtin_amdgcn_fdot2(a, b, c, false);      // v_dot2_f32_f16
#else
    return c + (float)a.x * (float)b.x + (float)a.y * (float)b.y;
#endif
}
// interleave two u32s of packed f16 pairs: pklo -> (b.lo16, a.lo16), pkhi -> (b.hi16, a.hi16)
__device__ __forceinline__ h2 pklo(unsigned a, unsigned b) {
    return u2h(__builtin_amdgcn_perm(a, b, 0x05040100u));
}
__device__ __forceinline__ h2 pkhi(unsigned a, unsigned b) {
    return u2h(__builtin_amdgcn_perm(a, b, 0x07060302u));
}
__device__ __forceinline__ unsigned short f2h(float f) {   // RNE f32->f16 bits
    _Float16 x = (_Float16)f;
    return __builtin_bit_cast(unsigned short, x);
}

// ---------------- CSR build: bucket sort ----------------

__global__ __launch_bounds__(256) void k_binA(const int* __restrict__ dsts,
                                              int* __restrict__ bcnt,
                                              int E, int Et, int NB) {
    __shared__ int hist[NBMAX];
    for (int i = threadIdx.x; i < NB; i += 256) hist[i] = 0;
    __syncthreads();
    int e0 = blockIdx.x * 2048;
#pragma unroll
    for (int it = 0; it < 8; ++it) {
        int e = e0 + it * 256 + threadIdx.x;
        if (e < Et) {
            int d = (e < E) ? dsts[e] : (e - E);
            atomicAdd(&hist[d >> 8], 1);
        }
    }
    __syncthreads();
    for (int i = threadIdx.x; i < NB; i += 256) {
        int c = hist[i];
        if (c) atomicAdd(&bcnt[i], c);
    }
}

__global__ __launch_bounds__(NBMAX) void k_binB(const int* __restrict__ bcnt,
                                                int* __restrict__ bbase,
                                                int* __restrict__ bcur,
                                                int* __restrict__ rp,
                                                int NB, int N, int Et) {
    __shared__ int sc[NBMAX];
    int t = threadIdx.x;
    int v = (t < NB) ? bcnt[t] : 0;
    sc[t] = v; __syncthreads();
    int x = v;
    for (int o = 1; o < NBMAX; o <<= 1) {
        int y = (t >= o) ? sc[t - o] : 0;
        __syncthreads();
        x += y;
        sc[t] = x;
        __syncthreads();
    }
    if (t < NB) { int b = x - v; bbase[t] = b; bcur[t] = b; }
    if (t == 0) rp[N] = Et;
}

__global__ __launch_bounds__(256) void k_binC(const int* __restrict__ srcs,
                                              const int* __restrict__ dsts,
                                              int* __restrict__ bcur,
                                              unsigned* __restrict__ binned,
                                              int E, int Et, int NB) {
    __shared__ int hist[NBMAX];
    __shared__ int gbase[NBMAX];
    __shared__ int lcnt[NBMAX];
    int t = threadIdx.x;
    for (int i = t; i < NB; i += 256) hist[i] = 0;
    __syncthreads();
    int e0 = blockIdx.x * CHUNK;
#pragma unroll 4
    for (int it = 0; it < CHUNK / 256; ++it) {
        int e = e0 + it * 256 + t;
        if (e < Et) {
            int d = (e < E) ? dsts[e] : (e - E);
            atomicAdd(&hist[d >> 8], 1);
        }
    }
    __syncthreads();
    for (int i = t; i < NB; i += 256) {
        int c = hist[i];
        gbase[i] = c ? atomicAdd(&bcur[i], c) : 0;
        lcnt[i] = 0;
    }
    __syncthreads();
#pragma unroll 4
    for (int it = 0; it < CHUNK / 256; ++it) {
        int e = e0 + it * 256 + t;
        if (e < Et) {
            int s, d;
            if (e < E) { s = srcs[e]; d = dsts[e]; } else { s = e - E; d = s; }
            int b = d >> 8;
            int p = atomicAdd(&lcnt[b], 1);
            binned[gbase[b] + p] = (unsigned)s | ((unsigned)(d & 255) << 24);
        }
    }
}

__global__ __launch_bounds__(256) void k_binD(const unsigned* __restrict__ binned,
                                              const int* __restrict__ bbase,
                                              const int* __restrict__ bcur,
                                              int* __restrict__ rp,
                                              int* __restrict__ csr, int N) {
    __shared__ int hist[256];
    __shared__ int sc[256];
    __shared__ int lcnt[256];
    int b = blockIdx.x, t = threadIdx.x;
    int base = bbase[b], end = bcur[b];
    hist[t] = 0; __syncthreads();
    for (int j = base + t; j < end; j += 256)
        atomicAdd(&hist[binned[j] >> 24], 1);
    __syncthreads();
    int v = hist[t];
    sc[t] = v; __syncthreads();
    int x = v;
    for (int o = 1; o < 256; o <<= 1) {
        int y = (t >= o) ? sc[t - o] : 0;
        __syncthreads();
        x += y;
        sc[t] = x;
        __syncthreads();
    }
    int pref = x - v;
    int g = (b << 8) + t;
    if (g < N) rp[g] = base + pref;
    sc[t] = pref;
    lcnt[t] = 0;
    __syncthreads();
    for (int j = base + t; j < end; j += 256) {
        unsigned w = binned[j];
        int v2 = (int)(w >> 24);
        int s = (int)(w & 0xFFFFFFu);
        int p = atomicAdd(&lcnt[v2], 1);
        csr[base + sc[v2] + p] = s;
    }
}

// ---------------- W1 split: fp32 [128][64] -> bf16-hi/lo transposed [64][128] ----------------

__global__ __launch_bounds__(256) void k_wsplit(const float* __restrict__ W,
                                                unsigned short* __restrict__ WhiT,
                                                unsigned short* __restrict__ WloT) {
    int i = blockIdx.x * 256 + threadIdx.x;
    if (i >= F_IN * F_H) return;
    int k = i >> 6, c = i & 63;                    // W[k][c], C = F_H = 64
    float w = W[i];
    unsigned u = __float_as_uint(w);
    unsigned hi = u & 0xFFFF0000u;                 // truncation split: residual
    float d = w - __uint_as_float(hi);             // captured exactly by lo
    WhiT[c * F_IN + k] = (unsigned short)(hi >> 16);
    WloT[c * F_IN + k] = (unsigned short)(__float_as_uint(d) >> 16);
}

// ---------------- GEMM1 (MFMA): h1 = f16(x @ W1), fused fp32 alphas ----------------
// r6: x-block staged through LDS with coalesced float4 loads (8/thread),
// row stride 132 floats (2-way bank aliasing on frag reads = free). LDS
// buffer aliased for the f16 output staging after the frag reads complete.

__global__ __launch_bounds__(256) void k_gemm1m(const float* __restrict__ x,
                                                const unsigned short* __restrict__ WhiT,
                                                const unsigned short* __restrict__ WloT,
                                                const float* __restrict__ avs,
                                                const float* __restrict__ avd,
                                                unsigned short* __restrict__ h,
                                                float* __restrict__ as,
                                                float* __restrict__ ad, int N) {
    __shared__ __align__(16) float xs[64][132];    // 33.8 KB; aliased as hs below
    unsigned short (*hs)[72] = (unsigned short(*)[72])xs;
    const int t = threadIdx.x;
    const int wv = t >> 6;
    const int lane = t & 63;
    const int lrow = lane & 15;
    const int lk8 = lane >> 4;
    const int r0 = blockIdx.x * 64;

    // coalesced stage: 64 rows x 32 float4 = 2048 float4, 8 per thread
    {
        const float4* xg = (const float4*)x;
#pragma unroll
        for (int it = 0; it < 8; ++it) {
            int flat = it * 256 + t;               // 0..2047
            int row = flat >> 5, c4 = flat & 31;
            int grow = min(r0 + row, N - 1);
            float4 v = xg[(size_t)grow * 32 + c4];
            *(float4*)&xs[row][c4 * 4] = v;
        }
    }
    __syncthreads();

    // frag load from LDS + split to bf16 hi/lo
    s16x8 ah[4], al[4];
#pragma unroll
    for (int kt = 0; kt < 4; ++kt) {
        const float* rp_ = &xs[wv * 16 + lrow][kt * 32 + lk8 * 8];
        float4 a = *(const float4*)rp_;
        float4 b = *(const float4*)(rp_ + 4);
        float e0[8] = {a.x, a.y, a.z, a.w, b.x, b.y, b.z, b.w};
        unsigned uh[4], ul[4];
#pragma unroll
        for (int p = 0; p < 4; ++p) {
            float a0 = e0[2 * p], a1 = e0[2 * p + 1];
            unsigned u0 = __float_as_uint(a0), u1 = __float_as_uint(a1);
            float d0 = a0 - __uint_as_float(u0 & 0xFFFF0000u);
            float d1 = a1 - __uint_as_float(u1 & 0xFFFF0000u);
            uh[p] = __builtin_amdgcn_perm(u1, u0, 0x07060302u);
            ul[p] = __builtin_amdgcn_perm(__float_as_uint(d1), __float_as_uint(d0), 0x07060302u);
        }
        ah[kt] = __builtin_bit_cast(s16x8, make_uint4(uh[0], uh[1], uh[2], uh[3]));
        al[kt] = __builtin_bit_cast(s16x8, make_uint4(ul[0], ul[1], ul[2], ul[3]));
    }
    __syncthreads();                               // xs reads done -> reuse as hs

    f32x4 acc[4] = {};                             // one 16x16 C-tile per ct
#pragma unroll
    for (int kt = 0; kt < 4; ++kt) {
#pragma unroll
        for (int ct = 0; ct < 4; ++ct) {
            const int boff = (ct * 16 + lrow) * F_IN + kt * 32 + lk8 * 8;
            s16x8 bh = *(const s16x8*)&WhiT[boff];
            s16x8 bl = *(const s16x8*)&WloT[boff];
            acc[ct] = __builtin_amdgcn_mfma_f32_16x16x32_bf16(ah[kt], bh, acc[ct], 0, 0, 0);
            acc[ct] = __builtin_amdgcn_mfma_f32_16x16x32_bf16(al[kt], bh, acc[ct], 0, 0, 0);
            acc[ct] = __builtin_amdgcn_mfma_f32_16x16x32_bf16(ah[kt], bl, acc[ct], 0, 0, 0);
        }
    }

    // fused alphas from fp32 accumulators: reduce over 16 cols (lrow groups)
    float avs_c[4], avd_c[4];
#pragma unroll
    for (int ct = 0; ct < 4; ++ct) {
        avs_c[ct] = avs[ct * 16 + lrow];
        avd_c[ct] = avd[ct * 16 + lrow];
    }
#pragma unroll
    for (int r = 0; r < 4; ++r) {
        float ps = acc[0][r] * avs_c[0] + acc[1][r] * avs_c[1]
                 + acc[2][r] * avs_c[2] + acc[3][r] * avs_c[3];
        float pd = acc[0][r] * avd_c[0] + acc[1][r] * avd_c[1]
                 + acc[2][r] * avd_c[2] + acc[3][r] * avd_c[3];
#pragma unroll
        for (int o = 8; o; o >>= 1) {
            ps += __shfl_xor(ps, o, 16);
            pd += __shfl_xor(pd, o, 16);
        }
        int orow = r0 + wv * 16 + lk8 * 4 + r;
        if (lrow == 0 && orow < N) { as[orow] = ps; ad[orow] = pd; }
    }

    // C -> LDS (f16) -> coalesced global store
#pragma unroll
    for (int ct = 0; ct < 4; ++ct)
#pragma unroll
        for (int r = 0; r < 4; ++r)
            hs[wv * 16 + lk8 * 4 + r][ct * 16 + lrow] = f2h(acc[ct][r]);
    __syncthreads();
    const int row = t >> 2, ch = t & 3;
    const int grow = r0 + row;
    if (grow < N) {
        uint4 v0 = *(const uint4*)&hs[row][ch * 16];
        uint4 v1 = *(const uint4*)&hs[row][ch * 16 + 8];
        uint4* gp = (uint4*)(h + (size_t)grow * F_H + ch * 16);
        gp[0] = v0; gp[1] = v1;
    }
}

// ---------------- GEMM2: h2 = f16(out1_f16 @ W2), COMPACT 40-col rows ----------------

__global__ __launch_bounds__(256) void k_gemm2(const unsigned short* __restrict__ xin,
                                               const float* __restrict__ W,
                                               const float* __restrict__ avs,
                                               const float* __restrict__ avd,
                                               unsigned short* __restrict__ h,
                                               float* __restrict__ as,
                                               float* __restrict__ ad, int N) {
    __shared__ __align__(16) float Ws[F_H * F_O];
    for (int i = threadIdx.x; i < F_H * F_O; i += 256) Ws[i] = W[i];
    __syncthreads();
    int t = threadIdx.x;
    int r0 = blockIdx.x * 64 + (t >> 3) * 2;
    int l = t & 7;
    if (r0 >= N) return;
    const uint2* xa = (const uint2*)(xin + (size_t)r0 * F_H);
    const uint2* xb = (const uint2*)(xin + (size_t)(r0 + 1) * F_H);
    float acca[5] = {}, accb[5] = {};
#pragma unroll
    for (int k4 = 0; k4 < F_H / 4; ++k4) {
        uint2 ua = xa[k4];
        uint2 ub = xb[k4];
        h2 a01 = u2h(ua.x), a23 = u2h(ua.y);
        h2 b01 = u2h(ub.x), b23 = u2h(ub.y);
        float xva[4] = {(float)a01.x, (float)a01.y, (float)a23.x, (float)a23.y};
        float xvb[4] = {(float)b01.x, (float)b01.y, (float)b23.x, (float)b23.y};
        int kb = k4 * 4;
#pragma unroll
        for (int kk = 0; kk < 4; ++kk) {
            const float* wr = &Ws[(kb + kk) * F_O + l];
            float w0 = wr[0], w1 = wr[8], w2 = wr[16], w3 = wr[24], w4 = wr[32];
            float xs = xva[kk];
            acca[0] += xs * w0; acca[1] += xs * w1; acca[2] += xs * w2;
            acca[3] += xs * w3; acca[4] += xs * w4;
            float ys = xvb[kk];
            accb[0] += ys * w0; accb[1] += ys * w1; accb[2] += ys * w2;
            accb[3] += ys * w3; accb[4] += ys * w4;
        }
    }
    float psa = 0.f, pda = 0.f, psb = 0.f, pdb = 0.f;
    unsigned short* ra = h + (size_t)r0 * F_O;     // compact row stride 40
    unsigned short* rb = h + (size_t)(r0 + 1) * F_O;
#pragma unroll
    for (int cc = 0; cc < 5; ++cc) {
        int c = l + 8 * cc;
        ra[c] = f2h(acca[cc]);
        rb[c] = f2h(accb[cc]);
        float vs = avs[c], vd = avd[c];
        psa += acca[cc] * vs; pda += acca[cc] * vd;
        psb += accb[cc] * vs; pdb += accb[cc] * vd;
    }
#pragma unroll
    for (int o = 4; o; o >>= 1) {
        psa += __shfl_xor(psa, o, 8);
        pda += __shfl_xor(pda, o, 8);
        psb += __shfl_xor(psb, o, 8);
        pdb += __shfl_xor(pdb, o, 8);
    }
    if (l == 0) { as[r0] = psa; ad[r0] = pda; as[r0 + 1] = psb; ad[r0 + 1] = pdb; }
}

// ---------------- Aggregation: 8 lanes per dst node, 8 nodes per wave ----------------
// Octet loop: edge list padded to x8 (w=0, src=self). ROWB = uint4 per h-row
// (8 for 64-col layer-1, 5 for compact 40-col layer-2; lanes >= ROWB clamp to
// the row base -- same cache line, results masked in the epilogue).

template <int FOUT, int ROWB, bool RELU, bool LOGSM, bool F16OUT>
__global__ __launch_bounds__(256) void k_agg(const int* __restrict__ rp,
                                             const int* __restrict__ csr,
                                             const float* __restrict__ as,
                                             const float* __restrict__ ad,
                                             const uint4* __restrict__ h4,
                                             const float* __restrict__ bias,
                                             void* __restrict__ outv, int N) {
    constexpr int CAP = 64;                        // LDS-resident edges per node
    __shared__ __align__(16) uint2 wsb[4][8][CAP + 2];
    const int w = threadIdx.x >> 6;
    const int g = (threadIdx.x >> 3) & 7;
    const int c = threadIdx.x & 7;
    const int cg = (c < ROWB) ? c : 0;             // gather slot (clamped)
    const int i = blockIdx.x * 32 + (threadIdx.x >> 3);
    if (i >= N) return;
    const int start = rp[i], end = rp[i + 1];
    const int deg = end - start;
    const int dm = min(deg, CAP);
    const int dmR8 = (dm + 7) & ~7;                // padded to x8 (<= CAP)
    const float adi = ad[i];

    // Phase A: compute edge weights into this group's LDS segment
    for (int idx = c; idx < dm; idx += 8) {
        int srcn = csr[start + idx];
        float e = as[srcn] + adi;
        e = fmaxf(e, 0.2f * e);                    // leaky_relu
        wsb[w][g][idx] = make_uint2(__float_as_uint(__expf(e)), (unsigned)srcn);
    }
    {   // pad (at most 7 entries): w=0, src=self
        int idx = dm + c;
        if (idx < dmR8) wsb[w][g][idx] = make_uint2(0u, (unsigned)i);
    }

    // Phase B: octet loop (same-wave LDS, no barrier needed)
    const uint4* pw = (const uint4*)wsb[w][g];
    float acc[8] = {}, acc2[8] = {};
    float sacc = 0.f;
    const int noct = dmR8 >> 3;
    for (int q = 0; q < noct; ++q) {
        uint4 m0 = pw[4 * q];                      // (w0,s0,w1,s1)
        uint4 m1 = pw[4 * q + 1];                  // (w2,s2,w3,s3)
        uint4 m2 = pw[4 * q + 2];                  // (w4,s4,w5,s5)
        uint4 m3 = pw[4 * q + 3];                  // (w6,s6,w7,s7)
        uint4 hv0 = h4[(size_t)m0.y * ROWB + cg];
        uint4 hv1 = h4[(size_t)m0.w * ROWB + cg];
        uint4 hv2 = h4[(size_t)m1.y * ROWB + cg];
        uint4 hv3 = h4[(size_t)m1.w * ROWB + cg];
        uint4 hv4 = h4[(size_t)m2.y * ROWB + cg];
        uint4 hv5 = h4[(size_t)m2.w * ROWB + cg];
        uint4 hv6 = h4[(size_t)m3.y * ROWB + cg];
        uint4 hv7 = h4[(size_t)m3.w * ROWB + cg];
        float w0 = __uint_as_float(m0.x), w1 = __uint_as_float(m0.z);
        float w2 = __uint_as_float(m1.x), w3 = __uint_as_float(m1.z);
        float w4 = __uint_as_float(m2.x), w5 = __uint_as_float(m2.z);
        float w6 = __uint_as_float(m3.x), w7 = __uint_as_float(m3.z);
        sacc += ((w0 + w1) + (w2 + w3)) + ((w4 + w5) + (w6 + w7));
        h2 wp0 = __builtin_amdgcn_cvt_pkrtz(w0, w1);
        h2 wp1 = __builtin_amdgcn_cvt_pkrtz(w2, w3);
        h2 wp2 = __builtin_amdgcn_cvt_pkrtz(w4, w5);
        h2 wp3 = __builtin_amdgcn_cvt_pkrtz(w6, w7);
        acc[0] = fdot2f(wp0, pklo(hv1.x, hv0.x), acc[0]);
        acc[1] = fdot2f(wp0, pkhi(hv1.x, hv0.x), acc[1]);
        acc[2] = fdot2f(wp0, pklo(hv1.y, hv0.y), acc[2]);
        acc[3] = fdot2f(wp0, pkhi(hv1.y, hv0.y), acc[3]);
        acc[4] = fdot2f(wp0, pklo(hv1.z, hv0.z), acc[4]);
        acc[5] = fdot2f(wp0, pkhi(hv1.z, hv0.z), acc[5]);
        acc[6] = fdot2f(wp0, pklo(hv1.w, hv0.w), acc[6]);
        acc[7] = fdot2f(wp0, pkhi(hv1.w, hv0.w), acc[7]);
        acc2[0] = fdot2f(wp1, pklo(hv3.x, hv2.x), acc2[0]);
        acc2[1] = fdot2f(wp1, pkhi(hv3.x, hv2.x), acc2[1]);
        acc2[2] = fdot2f(wp1, pklo(hv3.y, hv2.y), acc2[2]);
        acc2[3] = fdot2f(wp1, pkhi(hv3.y, hv2.y), acc2[3]);
        acc2[4] = fdot2f(wp1, pklo(hv3.z, hv2.z), acc2[4]);
        acc2[5] = fdot2f(wp1, pkhi(hv3.z, hv2.z), acc2[5]);
        acc2[6] = fdot2f(wp1, pklo(hv3.w, hv2.w), acc2[6]);
        acc2[7] = fdot2f(wp1, pkhi(hv3.w, hv2.w), acc2[7]);
        acc[0] = fdot2f(wp2, pklo(hv5.x, hv4.x), acc[0]);
        acc[1] = fdot2f(wp2, pkhi(hv5.x, hv4.x), acc[1]);
        acc[2] = fdot2f(wp2, pklo(hv5.y, hv4.y), acc[2]);
        acc[3] = fdot2f(wp2, pkhi(hv5.y, hv4.y), acc[3]);
        acc[4] = fdot2f(wp2, pklo(hv5.z, hv4.z), acc[4]);
        acc[5] = fdot2f(wp2, pkhi(hv5.z, hv4.z), acc[5]);
        acc[6] = fdot2f(wp2, pklo(hv5.w, hv4.w), acc[6]);
        acc[7] = fdot2f(wp2, pkhi(hv5.w, hv4.w), acc[7]);
        acc2[0] = fdot2f(wp3, pklo(hv7.x, hv6.x), acc2[0]);
        acc2[1] = fdot2f(wp3, pkhi(hv7.x, hv6.x), acc2[1]);
        acc2[2] = fdot2f(wp3, pklo(hv7.y, hv6.y), acc2[2]);
        acc2[3] = fdot2f(wp3, pkhi(hv7.y, hv6.y), acc2[3]);
        acc2[4] = fdot2f(wp3, pklo(hv7.z, hv6.z), acc2[4]);
        acc2[5] = fdot2f(wp3, pkhi(hv7.z, hv6.z), acc2[5]);
        acc2[6] = fdot2f(wp3, pklo(hv7.w, hv6.w), acc2[6]);
        acc2[7] = fdot2f(wp3, pkhi(hv7.w, hv6.w), acc2[7]);
    }

    // rare overflow tail (deg > CAP): single-edge, dup-pair trick with (w,0)
    for (int j = start + dm; j < end; ++j) {
        int srcn = csr[j];
        float e = as[srcn] + adi;
        e = fmaxf(e, 0.2f * e);
        float wv = __expf(e);
        sacc += wv;
        uint4 hv = h4[(size_t)srcn * ROWB + cg];
        h2 wp = __builtin_amdgcn_cvt_pkrtz(wv, 0.f);
        acc[0] = fdot2f(wp, pklo(hv.x, hv.x), acc[0]);
        acc[1] = fdot2f(wp, pkhi(hv.x, hv.x), acc[1]);
        acc[2] = fdot2f(wp, pklo(hv.y, hv.y), acc[2]);
        acc[3] = fdot2f(wp, pkhi(hv.y, hv.y), acc[3]);
        acc[4] = fdot2f(wp, pklo(hv.z, hv.z), acc[4]);
        acc[5] = fdot2f(wp, pkhi(hv.z, hv.z), acc[5]);
        acc[6] = fdot2f(wp, pklo(hv.w, hv.w), acc[6]);
        acc[7] = fdot2f(wp, pkhi(hv.w, hv.w), acc[7]);
    }

#pragma unroll
    for (int k = 0; k < 8; ++k) acc[k] += acc2[k];
    float inv = 1.f / sacc;                        // identical across the group

    if (!LOGSM) {
        float r[8];
#pragma unroll
        for (int k = 0; k < 8; ++k) {
            r[k] = fmaf(acc[k], inv, bias[8 * c + k]);
            if (RELU) r[k] = fmaxf(r[k], 0.f);
        }
        if (F16OUT) {                              // f16 rows, stride 64 (= F_H)
            unsigned short* oh = (unsigned short*)outv;
            unsigned u0 = (unsigned)f2h(r[0]) | ((unsigned)f2h(r[1]) << 16);
            unsigned u1 = (unsigned)f2h(r[2]) | ((unsigned)f2h(r[3]) << 16);
            unsigned u2 = (unsigned)f2h(r[4]) | ((unsigned)f2h(r[5]) << 16);
            unsigned u3 = (unsigned)f2h(r[6]) | ((unsigned)f2h(r[7]) << 16);
            *(uint4*)(oh + (size_t)i * F_H + 8 * c) = make_uint4(u0, u1, u2, u3);
        } else {
            float* out = (float*)outv;
            float4* op = (float4*)(out + (size_t)i * FOUT + 8 * c);
            op[0] = make_float4(r[0], r[1], r[2], r[3]);
            op[1] = make_float4(r[4], r[5], r[6], r[7]);
        }
    } else {
        float* out = (float*)outv;
        constexpr int VC = FOUT / 8;               // valid lane-chunks (5 for FOUT=40)
        bool act = (c < VC);
        float v[8];
#pragma unroll
        for (int k = 0; k < 8; ++k) {
            float bv = bias[act ? 8 * c + k : 0];
            v[k] = act ? fmaf(acc[k], inv, bv) : -INFINITY;
        }
        float mx = v[0];
#pragma unroll
        for (int k = 1; k < 8; ++k) mx = fmaxf(mx, v[k]);
#pragma unroll
        for (int o = 1; o <= 4; o <<= 1) mx = fmaxf(mx, __shfl_xor(mx, o));  // within 8-lane group
        float es = 0.f;
        if (act) {
#pragma unroll
            for (int k = 0; k < 8; ++k) es += __expf(v[k] - mx);
        }
#pragma unroll
        for (int o = 1; o <= 4; o <<= 1) es += __shfl_xor(es, o);
        if (act) {
            float lse = mx + __logf(es);
            float4* op = (float4*)(out + (size_t)i * FOUT + 8 * c);
            op[0] = make_float4(v[0] - lse, v[1] - lse, v[2] - lse, v[3] - lse);
            op[1] = make_float4(v[4] - lse, v[5] - lse, v[6] - lse, v[7] - lse);
        }
    }
}

// ---------------- launch ----------------

extern "C" void kernel_launch(void* const* d_in, const int* in_sizes, int n_in,
                              void* d_out, int out_size, void* d_ws, size_t ws_size,
                              hipStream_t stream) {
    const float* x   = (const float*)d_in[0];
    const int* edges = (const int*)d_in[1];
    const float* W1  = (const float*)d_in[2];
    const float* av_s1 = (const float*)d_in[3];
    const float* av_d1 = (const float*)d_in[4];
    const float* b1  = (const float*)d_in[5];
    const float* W2  = (const float*)d_in[6];
    const float* av_s2 = (const float*)d_in[7];
    const float* av_d2 = (const float*)d_in[8];
    const float* b2  = (const float*)d_in[9];
    float* out = (float*)d_out;

    const int N  = in_sizes[0] / F_IN;
    const int E  = in_sizes[1] / 2;
    const int Et = E + N;
    const int NB = (N + 255) >> 8;

    char* p = (char*)d_ws;
    auto alloc = [&](size_t bytes) {
        char* q = p;
        p += (bytes + 255) & ~(size_t)255;
        return (void*)q;
    };
    unsigned short* h1 = (unsigned short*)alloc((size_t)N * F_H * 2);  // f16 [N][64]; reused as compact h2 [N][40]
    unsigned short* out1h = (unsigned short*)alloc((size_t)N * F_H * 2);  // f16 agg1 output [N][64]
    float* as1    = (float*)alloc((size_t)N * 4);
    float* ad1    = (float*)alloc((size_t)N * 4);
    float* as2    = (float*)alloc((size_t)N * 4);
    float* ad2    = (float*)alloc((size_t)N * 4);
    int* rp       = (int*)alloc((size_t)(N + 1) * 4);
    int* bcnt     = (int*)alloc(NBMAX * 4);
    int* bbase    = (int*)alloc(NBMAX * 4);
    int* bcur     = (int*)alloc(NBMAX * 4);
    unsigned* binned = (unsigned*)alloc((size_t)Et * 4);
    int* csr      = (int*)alloc((size_t)Et * 4);
    unsigned short* WhiT = (unsigned short*)alloc((size_t)F_H * F_IN * 2);
    unsigned short* WloT = (unsigned short*)alloc((size_t)F_H * F_IN * 2);
    (void)n_in; (void)out_size; (void)ws_size;

    const int* srcs = edges;
    const int* dsts = edges + E;

    hipMemsetAsync(bcnt, 0, NBMAX * 4, stream);

    k_wsplit<<<(F_IN * F_H + 255) / 256, 256, 0, stream>>>(W1, WhiT, WloT);
    k_binA<<<(Et + 2047) / 2048, 256, 0, stream>>>(dsts, bcnt, E, Et, NB);
    k_binB<<<1, NBMAX, 0, stream>>>(bcnt, bbase, bcur, rp, NB, N, Et);
    k_binC<<<(Et + CHUNK - 1) / CHUNK, 256, 0, stream>>>(srcs, dsts, bcur, binned, E, Et, NB);
    k_binD<<<NB, 256, 0, stream>>>(binned, bbase, bcur, rp, csr, N);

    k_gemm1m<<<(N + 63) / 64, 256, 0, stream>>>(x, WhiT, WloT, av_s1, av_d1, h1, as1, ad1, N);
    int gAgg = (N + 31) / 32;
    k_agg<F_H, 8, true, false, true><<<gAgg, 256, 0, stream>>>(rp, csr, as1, ad1,
                                                               (const uint4*)h1, b1, out1h, N);
    k_gemm2<<<(N + 63) / 64, 256, 0, stream>>>(out1h, W2, av_s2, av_d2, h1, as2, ad2, N);
    k_agg<F_O, 5, false, true, false><<<gAgg, 256, 0, stream>>>(rp, csr, as2, ad2,
                                                                (const uint4*)h1, b2, out, N);
}

// Round 7
// 290.603 us; speedup vs baseline: 2.0183x; 1.0044x over previous
//
#include <hip/hip_runtime.h>
#include <math.h>

// GAT 2-layer, N=100K nodes, E=1.6M edges (+N self loops), fp32 compute,
// f16 feature rows for the edge gather.
// CSR build via 2-level bucket sort (bucket = dst>>8).
// agg: 8 lanes per dst node, 8 nodes per wave, octet unroll, f16 pair-dot.
//   Layer-1 h1: [N][64] f16 (128B rows, 2 sectors/edge -- at compulsory
//   L3->L2 floor ~95MB = 12.8MB x ~7.1 XCDs).
//   Layer-2 SPLIT tables (r7): T0 = cols 0..31 (64B rows, 1 aligned sector
//   per edge), T1 = cols 32..39 (16B rows, 1.6MB table -> L2-resident).
//   r6 compact-80B REVERTED: unaligned 80B rows cost ~2.25 sectors (FETCH
//   88->95MB) -- sector alignment beats byte compaction.
// gemm1 MFMA 3-pass truncation-split bf16, x staged via coalesced LDS.

constexpr int F_IN = 128;
constexpr int F_H  = 64;
constexpr int F_O  = 40;
constexpr int NBMAX = 512;      // max buckets (N <= 131072)
constexpr int CHUNK = 8192;     // edges per block in k_binC

using h2 = decltype(__builtin_amdgcn_cvt_pkrtz(0.f, 0.f));   // <2 x half>
typedef __attribute__((ext_vector_type(4))) float f32x4;
typedef __attribute__((ext_vector_type(8))) short s16x8;

__device__ __forceinline__ h2 u2h(unsigned u) { return __builtin_bit_cast(h2, u); }

__device__ __forceinline__ float fdot2f(h2 a, h2 b, float c) {
#if __has_builtin(__builtin_amdgcn_fdot2)
    return __builtin_amdgcn_fdot2(a, b, c, false);      // v_dot2_f32_f16
#else
    return c + (float)a.x * (float)b.x + (float)a.y * (float)b.y;
#endif
}
// interleave two u32s of packed f16 pairs: pklo -> (b.lo16, a.lo16), pkhi -> (b.hi16, a.hi16)
__device__ __forceinline__ h2 pklo(unsigned a, unsigned b) {
    return u2h(__builtin_amdgcn_perm(a, b, 0x05040100u));
}
__device__ __forceinline__ h2 pkhi(unsigned a, unsigned b) {
    return u2h(__builtin_amdgcn_perm(a, b, 0x07060302u));
}
__device__ __forceinline__ unsigned short f2h(float f) {   // RNE f32->f16 bits
    _Float16 x = (_Float16)f;
    return __builtin_bit_cast(unsigned short, x);
}

// ---------------- CSR build: bucket sort ----------------

__global__ __launch_bounds__(256) void k_binA(const int* __restrict__ dsts,
                                              int* __restrict__ bcnt,
                                              int E, int Et, int NB) {
    __shared__ int hist[NBMAX];
    for (int i = threadIdx.x; i < NB; i += 256) hist[i] = 0;
    __syncthreads();
    int e0 = blockIdx.x * 2048;
#pragma unroll
    for (int it = 0; it < 8; ++it) {
        int e = e0 + it * 256 + threadIdx.x;
        if (e < Et) {
            int d = (e < E) ? dsts[e] : (e - E);
            atomicAdd(&hist[d >> 8], 1);
        }
    }
    __syncthreads();
    for (int i = threadIdx.x; i < NB; i += 256) {
        int c = hist[i];
        if (c) atomicAdd(&bcnt[i], c);
    }
}

__global__ __launch_bounds__(NBMAX) void k_binB(const int* __restrict__ bcnt,
                                                int* __restrict__ bbase,
                                                int* __restrict__ bcur,
                                                int* __restrict__ rp,
                                                int NB, int N, int Et) {
    __shared__ int sc[NBMAX];
    int t = threadIdx.x;
    int v = (t < NB) ? bcnt[t] : 0;
    sc[t] = v; __syncthreads();
    int x = v;
    for (int o = 1; o < NBMAX; o <<= 1) {
        int y = (t >= o) ? sc[t - o] : 0;
        __syncthreads();
        x += y;
        sc[t] = x;
        __syncthreads();
    }
    if (t < NB) { int b = x - v; bbase[t] = b; bcur[t] = b; }
    if (t == 0) rp[N] = Et;
}

__global__ __launch_bounds__(256) void k_binC(const int* __restrict__ srcs,
                                              const int* __restrict__ dsts,
                                              int* __restrict__ bcur,
                                              unsigned* __restrict__ binned,
                                              int E, int Et, int NB) {
    __shared__ int hist[NBMAX];
    __shared__ int gbase[NBMAX];
    __shared__ int lcnt[NBMAX];
    int t = threadIdx.x;
    for (int i = t; i < NB; i += 256) hist[i] = 0;
    __syncthreads();
    int e0 = blockIdx.x * CHUNK;
#pragma unroll 4
    for (int it = 0; it < CHUNK / 256; ++it) {
        int e = e0 + it * 256 + t;
        if (e < Et) {
            int d = (e < E) ? dsts[e] : (e - E);
            atomicAdd(&hist[d >> 8], 1);
        }
    }
    __syncthreads();
    for (int i = t; i < NB; i += 256) {
        int c = hist[i];
        gbase[i] = c ? atomicAdd(&bcur[i], c) : 0;
        lcnt[i] = 0;
    }
    __syncthreads();
#pragma unroll 4
    for (int it = 0; it < CHUNK / 256; ++it) {
        int e = e0 + it * 256 + t;
        if (e < Et) {
            int s, d;
            if (e < E) { s = srcs[e]; d = dsts[e]; } else { s = e - E; d = s; }
            int b = d >> 8;
            int p = atomicAdd(&lcnt[b], 1);
            binned[gbase[b] + p] = (unsigned)s | ((unsigned)(d & 255) << 24);
        }
    }
}

__global__ __launch_bounds__(256) void k_binD(const unsigned* __restrict__ binned,
                                              const int* __restrict__ bbase,
                                              const int* __restrict__ bcur,
                                              int* __restrict__ rp,
                                              int* __restrict__ csr, int N) {
    __shared__ int hist[256];
    __shared__ int sc[256];
    __shared__ int lcnt[256];
    int b = blockIdx.x, t = threadIdx.x;
    int base = bbase[b], end = bcur[b];
    hist[t] = 0; __syncthreads();
    for (int j = base + t; j < end; j += 256)
        atomicAdd(&hist[binned[j] >> 24], 1);
    __syncthreads();
    int v = hist[t];
    sc[t] = v; __syncthreads();
    int x = v;
    for (int o = 1; o < 256; o <<= 1) {
        int y = (t >= o) ? sc[t - o] : 0;
        __syncthreads();
        x += y;
        sc[t] = x;
        __syncthreads();
    }
    int pref = x - v;
    int g = (b << 8) + t;
    if (g < N) rp[g] = base + pref;
    sc[t] = pref;
    lcnt[t] = 0;
    __syncthreads();
    for (int j = base + t; j < end; j += 256) {
        unsigned w = binned[j];
        int v2 = (int)(w >> 24);
        int s = (int)(w & 0xFFFFFFu);
        int p = atomicAdd(&lcnt[v2], 1);
        csr[base + sc[v2] + p] = s;
    }
}

// ---------------- W1 split: fp32 [128][64] -> bf16-hi/lo transposed [64][128] ----------------

__global__ __launch_bounds__(256) void k_wsplit(const float* __restrict__ W,
                                                unsigned short* __restrict__ WhiT,
                                                unsigned short* __restrict__ WloT) {
    int i = blockIdx.x * 256 + threadIdx.x;
    if (i >= F_IN * F_H) return;
    int k = i >> 6, c = i & 63;                    // W[k][c], C = F_H = 64
    float w = W[i];
    unsigned u = __float_as_uint(w);
    unsigned hi = u & 0xFFFF0000u;                 // truncation split: residual
    float d = w - __uint_as_float(hi);             // captured exactly by lo
    WhiT[c * F_IN + k] = (unsigned short)(hi >> 16);
    WloT[c * F_IN + k] = (unsigned short)(__float_as_uint(d) >> 16);
}

// ---------------- GEMM1 (MFMA): h1 = f16(x @ W1), fused fp32 alphas ----------------

__global__ __launch_bounds__(256) void k_gemm1m(const float* __restrict__ x,
                                                const unsigned short* __restrict__ WhiT,
                                                const unsigned short* __restrict__ WloT,
                                                const float* __restrict__ avs,
                                                const float* __restrict__ avd,
                                                unsigned short* __restrict__ h,
                                                float* __restrict__ as,
                                                float* __restrict__ ad, int N) {
    __shared__ __align__(16) float xs[64][132];    // 33.8 KB; aliased as hs below
    unsigned short (*hs)[72] = (unsigned short(*)[72])xs;
    const int t = threadIdx.x;
    const int wv = t >> 6;
    const int lane = t & 63;
    const int lrow = lane & 15;
    const int lk8 = lane >> 4;
    const int r0 = blockIdx.x * 64;

    // coalesced stage: 64 rows x 32 float4 = 2048 float4, 8 per thread
    {
        const float4* xg = (const float4*)x;
#pragma unroll
        for (int it = 0; it < 8; ++it) {
            int flat = it * 256 + t;               // 0..2047
            int row = flat >> 5, c4 = flat & 31;
            int grow = min(r0 + row, N - 1);
            float4 v = xg[(size_t)grow * 32 + c4];
            *(float4*)&xs[row][c4 * 4] = v;
        }
    }
    __syncthreads();

    // frag load from LDS + split to bf16 hi/lo
    s16x8 ah[4], al[4];
#pragma unroll
    for (int kt = 0; kt < 4; ++kt) {
        const float* rp_ = &xs[wv * 16 + lrow][kt * 32 + lk8 * 8];
        float4 a = *(const float4*)rp_;
        float4 b = *(const float4*)(rp_ + 4);
        float e0[8] = {a.x, a.y, a.z, a.w, b.x, b.y, b.z, b.w};
        unsigned uh[4], ul[4];
#pragma unroll
        for (int p = 0; p < 4; ++p) {
            float a0 = e0[2 * p], a1 = e0[2 * p + 1];
            unsigned u0 = __float_as_uint(a0), u1 = __float_as_uint(a1);
            float d0 = a0 - __uint_as_float(u0 & 0xFFFF0000u);
            float d1 = a1 - __uint_as_float(u1 & 0xFFFF0000u);
            uh[p] = __builtin_amdgcn_perm(u1, u0, 0x07060302u);
            ul[p] = __builtin_amdgcn_perm(__float_as_uint(d1), __float_as_uint(d0), 0x07060302u);
        }
        ah[kt] = __builtin_bit_cast(s16x8, make_uint4(uh[0], uh[1], uh[2], uh[3]));
        al[kt] = __builtin_bit_cast(s16x8, make_uint4(ul[0], ul[1], ul[2], ul[3]));
    }
    __syncthreads();                               // xs reads done -> reuse as hs

    f32x4 acc[4] = {};                             // one 16x16 C-tile per ct
#pragma unroll
    for (int kt = 0; kt < 4; ++kt) {
#pragma unroll
        for (int ct = 0; ct < 4; ++ct) {
            const int boff = (ct * 16 + lrow) * F_IN + kt * 32 + lk8 * 8;
            s16x8 bh = *(const s16x8*)&WhiT[boff];
            s16x8 bl = *(const s16x8*)&WloT[boff];
            acc[ct] = __builtin_amdgcn_mfma_f32_16x16x32_bf16(ah[kt], bh, acc[ct], 0, 0, 0);
            acc[ct] = __builtin_amdgcn_mfma_f32_16x16x32_bf16(al[kt], bh, acc[ct], 0, 0, 0);
            acc[ct] = __builtin_amdgcn_mfma_f32_16x16x32_bf16(ah[kt], bl, acc[ct], 0, 0, 0);
        }
    }

    // fused alphas from fp32 accumulators: reduce over 16 cols (lrow groups)
    float avs_c[4], avd_c[4];
#pragma unroll
    for (int ct = 0; ct < 4; ++ct) {
        avs_c[ct] = avs[ct * 16 + lrow];
        avd_c[ct] = avd[ct * 16 + lrow];
    }
#pragma unroll
    for (int r = 0; r < 4; ++r) {
        float ps = acc[0][r] * avs_c[0] + acc[1][r] * avs_c[1]
                 + acc[2][r] * avs_c[2] + acc[3][r] * avs_c[3];
        float pd = acc[0][r] * avd_c[0] + acc[1][r] * avd_c[1]
                 + acc[2][r] * avd_c[2] + acc[3][r] * avd_c[3];
#pragma unroll
        for (int o = 8; o; o >>= 1) {
            ps += __shfl_xor(ps, o, 16);
            pd += __shfl_xor(pd, o, 16);
        }
        int orow = r0 + wv * 16 + lk8 * 4 + r;
        if (lrow == 0 && orow < N) { as[orow] = ps; ad[orow] = pd; }
    }

    // C -> LDS (f16) -> coalesced global store
#pragma unroll
    for (int ct = 0; ct < 4; ++ct)
#pragma unroll
        for (int r = 0; r < 4; ++r)
            hs[wv * 16 + lk8 * 4 + r][ct * 16 + lrow] = f2h(acc[ct][r]);
    __syncthreads();
    const int row = t >> 2, ch = t & 3;
    const int grow = r0 + row;
    if (grow < N) {
        uint4 v0 = *(const uint4*)&hs[row][ch * 16];
        uint4 v1 = *(const uint4*)&hs[row][ch * 16 + 8];
        uint4* gp = (uint4*)(h + (size_t)grow * F_H + ch * 16);
        gp[0] = v0; gp[1] = v1;
    }
}

// ---------------- GEMM2: h2 = f16(out1_f16 @ W2) -> split tables T0/T1 ----------------
// T0: cols 0..31, 64B rows (one aligned sector). T1: cols 32..39, 16B rows
// (1.6MB table, L2-resident for the agg2 gather).

__global__ __launch_bounds__(256) void k_gemm2(const unsigned short* __restrict__ xin,
                                               const float* __restrict__ W,
                                               const float* __restrict__ avs,
                                               const float* __restrict__ avd,
                                               unsigned short* __restrict__ t0,
                                               unsigned short* __restrict__ t1,
                                               float* __restrict__ as,
                                               float* __restrict__ ad, int N) {
    __shared__ __align__(16) float Ws[F_H * F_O];
    for (int i = threadIdx.x; i < F_H * F_O; i += 256) Ws[i] = W[i];
    __syncthreads();
    int t = threadIdx.x;
    int r0 = blockIdx.x * 64 + (t >> 3) * 2;
    int l = t & 7;
    if (r0 >= N) return;
    const uint2* xa = (const uint2*)(xin + (size_t)r0 * F_H);
    const uint2* xb = (const uint2*)(xin + (size_t)(r0 + 1) * F_H);
    float acca[5] = {}, accb[5] = {};
#pragma unroll
    for (int k4 = 0; k4 < F_H / 4; ++k4) {
        uint2 ua = xa[k4];
        uint2 ub = xb[k4];
        h2 a01 = u2h(ua.x), a23 = u2h(ua.y);
        h2 b01 = u2h(ub.x), b23 = u2h(ub.y);
        float xva[4] = {(float)a01.x, (float)a01.y, (float)a23.x, (float)a23.y};
        float xvb[4] = {(float)b01.x, (float)b01.y, (float)b23.x, (float)b23.y};
        int kb = k4 * 4;
#pragma unroll
        for (int kk = 0; kk < 4; ++kk) {
            const float* wr = &Ws[(kb + kk) * F_O + l];
            float w0 = wr[0], w1 = wr[8], w2 = wr[16], w3 = wr[24], w4 = wr[32];
            float xs = xva[kk];
            acca[0] += xs * w0; acca[1] += xs * w1; acca[2] += xs * w2;
            acca[3] += xs * w3; acca[4] += xs * w4;
            float ys = xvb[kk];
            accb[0] += ys * w0; accb[1] += ys * w1; accb[2] += ys * w2;
            accb[3] += ys * w3; accb[4] += ys * w4;
        }
    }
    float psa = 0.f, pda = 0.f, psb = 0.f, pdb = 0.f;
    unsigned short* ra0 = t0 + (size_t)r0 * 32;    // cols 0..31
    unsigned short* rb0 = t0 + (size_t)(r0 + 1) * 32;
#pragma unroll
    for (int cc = 0; cc < 4; ++cc) {
        int c = l + 8 * cc;
        ra0[c] = f2h(acca[cc]);
        rb0[c] = f2h(accb[cc]);
        float vs = avs[c], vd = avd[c];
        psa += acca[cc] * vs; pda += acca[cc] * vd;
        psb += accb[cc] * vs; pdb += accb[cc] * vd;
    }
    {   // cols 32..39 -> T1
        int c = l + 32;
        t1[(size_t)r0 * 8 + l] = f2h(acca[4]);
        t1[(size_t)(r0 + 1) * 8 + l] = f2h(accb[4]);
        float vs = avs[c], vd = avd[c];
        psa += acca[4] * vs; pda += acca[4] * vd;
        psb += accb[4] * vs; pdb += accb[4] * vd;
    }
#pragma unroll
    for (int o = 4; o; o >>= 1) {
        psa += __shfl_xor(psa, o, 8);
        pda += __shfl_xor(pda, o, 8);
        psb += __shfl_xor(psb, o, 8);
        pdb += __shfl_xor(pdb, o, 8);
    }
    if (l == 0) { as[r0] = psa; ad[r0] = pda; as[r0 + 1] = psb; ad[r0 + 1] = pdb; }
}

// ---------------- Aggregation: 8 lanes per dst node, 8 nodes per wave ----------------
// Octet loop, 8 gathers in flight. SPLIT=false (layer 1): lane c reads
// h4[src*8+c] (128B rows). SPLIT=true (layer 2): lanes 0..3 read T0[src*4+c]
// (one 64B sector), lanes 4..7 all read T1[src] (16B row, L2-resident table;
// identical addresses coalesce).

template <int FOUT, bool SPLIT, bool RELU, bool LOGSM, bool F16OUT>
__global__ __launch_bounds__(256) void k_agg(const int* __restrict__ rp,
                                             const int* __restrict__ csr,
                                             const float* __restrict__ as,
                                             const float* __restrict__ ad,
                                             const uint4* __restrict__ h4,
                                             const uint4* __restrict__ t1t,
                                             const float* __restrict__ bias,
                                             void* __restrict__ outv, int N) {
    constexpr int CAP = 64;                        // LDS-resident edges per node
    __shared__ __align__(16) uint2 wsb[4][8][CAP + 2];
    const int w = threadIdx.x >> 6;
    const int g = (threadIdx.x >> 3) & 7;
    const int c = threadIdx.x & 7;
    const int i = blockIdx.x * 32 + (threadIdx.x >> 3);
    if (i >= N) return;
    // per-lane gather base and per-src stride (uint4 units)
    const uint4* bp;
    size_t str;
    if (SPLIT) {
        if (c < 4) { bp = h4 + c; str = 4; }       // T0: 4 uint4 per row
        else       { bp = t1t;    str = 1; }       // T1: 1 uint4 per row
    } else {
        bp = h4 + c; str = 8;                      // 8 uint4 per row
    }
    const int start = rp[i], end = rp[i + 1];
    const int deg = end - start;
    const int dm = min(deg, CAP);
    const int dmR8 = (dm + 7) & ~7;                // padded to x8 (<= CAP)
    const float adi = ad[i];

    // Phase A: compute edge weights into this group's LDS segment
    for (int idx = c; idx < dm; idx += 8) {
        int srcn = csr[start + idx];
        float e = as[srcn] + adi;
        e = fmaxf(e, 0.2f * e);                    // leaky_relu
        wsb[w][g][idx] = make_uint2(__float_as_uint(__expf(e)), (unsigned)srcn);
    }
    {   // pad (at most 7 entries): w=0, src=self
        int idx = dm + c;
        if (idx < dmR8) wsb[w][g][idx] = make_uint2(0u, (unsigned)i);
    }

    // Phase B: octet loop (same-wave LDS, no barrier needed)
    const uint4* pw = (const uint4*)wsb[w][g];
    float acc[8] = {}, acc2[8] = {};
    float sacc = 0.f;
    const int noct = dmR8 >> 3;
    for (int q = 0; q < noct; ++q) {
        uint4 m0 = pw[4 * q];                      // (w0,s0,w1,s1)
        uint4 m1 = pw[4 * q + 1];                  // (w2,s2,w3,s3)
        uint4 m2 = pw[4 * q + 2];                  // (w4,s4,w5,s5)
        uint4 m3 = pw[4 * q + 3];                  // (w6,s6,w7,s7)
        uint4 hv0 = bp[(size_t)m0.y * str];
        uint4 hv1 = bp[(size_t)m0.w * str];
        uint4 hv2 = bp[(size_t)m1.y * str];
        uint4 hv3 = bp[(size_t)m1.w * str];
        uint4 hv4 = bp[(size_t)m2.y * str];
        uint4 hv5 = bp[(size_t)m2.w * str];
        uint4 hv6 = bp[(size_t)m3.y * str];
        uint4 hv7 = bp[(size_t)m3.w * str];
        float w0 = __uint_as_float(m0.x), w1 = __uint_as_float(m0.z);
        float w2 = __uint_as_float(m1.x), w3 = __uint_as_float(m1.z);
        float w4 = __uint_as_float(m2.x), w5 = __uint_as_float(m2.z);
        float w6 = __uint_as_float(m3.x), w7 = __uint_as_float(m3.z);
        sacc += ((w0 + w1) + (w2 + w3)) + ((w4 + w5) + (w6 + w7));
        h2 wp0 = __builtin_amdgcn_cvt_pkrtz(w0, w1);
        h2 wp1 = __builtin_amdgcn_cvt_pkrtz(w2, w3);
        h2 wp2 = __builtin_amdgcn_cvt_pkrtz(w4, w5);
        h2 wp3 = __builtin_amdgcn_cvt_pkrtz(w6, w7);
        acc[0] = fdot2f(wp0, pklo(hv1.x, hv0.x), acc[0]);
        acc[1] = fdot2f(wp0, pkhi(hv1.x, hv0.x), acc[1]);
        acc[2] = fdot2f(wp0, pklo(hv1.y, hv0.y), acc[2]);
        acc[3] = fdot2f(wp0, pkhi(hv1.y, hv0.y), acc[3]);
        acc[4] = fdot2f(wp0, pklo(hv1.z, hv0.z), acc[4]);
        acc[5] = fdot2f(wp0, pkhi(hv1.z, hv0.z), acc[5]);
        acc[6] = fdot2f(wp0, pklo(hv1.w, hv0.w), acc[6]);
        acc[7] = fdot2f(wp0, pkhi(hv1.w, hv0.w), acc[7]);
        acc2[0] = fdot2f(wp1, pklo(hv3.x, hv2.x), acc2[0]);
        acc2[1] = fdot2f(wp1, pkhi(hv3.x, hv2.x), acc2[1]);
        acc2[2] = fdot2f(wp1, pklo(hv3.y, hv2.y), acc2[2]);
        acc2[3] = fdot2f(wp1, pkhi(hv3.y, hv2.y), acc2[3]);
        acc2[4] = fdot2f(wp1, pklo(hv3.z, hv2.z), acc2[4]);
        acc2[5] = fdot2f(wp1, pkhi(hv3.z, hv2.z), acc2[5]);
        acc2[6] = fdot2f(wp1, pklo(hv3.w, hv2.w), acc2[6]);
        acc2[7] = fdot2f(wp1, pkhi(hv3.w, hv2.w), acc2[7]);
        acc[0] = fdot2f(wp2, pklo(hv5.x, hv4.x), acc[0]);
        acc[1] = fdot2f(wp2, pkhi(hv5.x, hv4.x), acc[1]);
        acc[2] = fdot2f(wp2, pklo(hv5.y, hv4.y), acc[2]);
        acc[3] = fdot2f(wp2, pkhi(hv5.y, hv4.y), acc[3]);
        acc[4] = fdot2f(wp2, pklo(hv5.z, hv4.z), acc[4]);
        acc[5] = fdot2f(wp2, pkhi(hv5.z, hv4.z), acc[5]);
        acc[6] = fdot2f(wp2, pklo(hv5.w, hv4.w), acc[6]);
        acc[7] = fdot2f(wp2, pkhi(hv5.w, hv4.w), acc[7]);
        acc2[0] = fdot2f(wp3, pklo(hv7.x, hv6.x), acc2[0]);
        acc2[1] = fdot2f(wp3, pkhi(hv7.x, hv6.x), acc2[1]);
        acc2[2] = fdot2f(wp3, pklo(hv7.y, hv6.y), acc2[2]);
        acc2[3] = fdot2f(wp3, pkhi(hv7.y, hv6.y), acc2[3]);
        acc2[4] = fdot2f(wp3, pklo(hv7.z, hv6.z), acc2[4]);
        acc2[5] = fdot2f(wp3, pkhi(hv7.z, hv6.z), acc2[5]);
        acc2[6] = fdot2f(wp3, pklo(hv7.w, hv6.w), acc2[6]);
        acc2[7] = fdot2f(wp3, pkhi(hv7.w, hv6.w), acc2[7]);
    }

    // rare overflow tail (deg > CAP): single-edge, dup-pair trick with (w,0)
    for (int j = start + dm; j < end; ++j) {
        int srcn = csr[j];
        float e = as[srcn] + adi;
        e = fmaxf(e, 0.2f * e);
        float wv = __expf(e);
        sacc += wv;
        uint4 hv = bp[(size_t)srcn * str];
        h2 wp = __builtin_amdgcn_cvt_pkrtz(wv, 0.f);
        acc[0] = fdot2f(wp, pklo(hv.x, hv.x), acc[0]);
        acc[1] = fdot2f(wp, pkhi(hv.x, hv.x), acc[1]);
        acc[2] = fdot2f(wp, pklo(hv.y, hv.y), acc[2]);
        acc[3] = fdot2f(wp, pkhi(hv.y, hv.y), acc[3]);
        acc[4] = fdot2f(wp, pklo(hv.z, hv.z), acc[4]);
        acc[5] = fdot2f(wp, pkhi(hv.z, hv.z), acc[5]);
        acc[6] = fdot2f(wp, pklo(hv.w, hv.w), acc[6]);
        acc[7] = fdot2f(wp, pkhi(hv.w, hv.w), acc[7]);
    }

#pragma unroll
    for (int k = 0; k < 8; ++k) acc[k] += acc2[k];
    float inv = 1.f / sacc;                        // identical across the group

    if (!LOGSM) {
        float r[8];
#pragma unroll
        for (int k = 0; k < 8; ++k) {
            r[k] = fmaf(acc[k], inv, bias[8 * c + k]);
            if (RELU) r[k] = fmaxf(r[k], 0.f);
        }
        if (F16OUT) {                              // f16 rows, stride 64 (= F_H)
            unsigned short* oh = (unsigned short*)outv;
            unsigned u0 = (unsigned)f2h(r[0]) | ((unsigned)f2h(r[1]) << 16);
            unsigned u1 = (unsigned)f2h(r[2]) | ((unsigned)f2h(r[3]) << 16);
            unsigned u2 = (unsigned)f2h(r[4]) | ((unsigned)f2h(r[5]) << 16);
            unsigned u3 = (unsigned)f2h(r[6]) | ((unsigned)f2h(r[7]) << 16);
            *(uint4*)(oh + (size_t)i * F_H + 8 * c) = make_uint4(u0, u1, u2, u3);
        } else {
            float* out = (float*)outv;
            float4* op = (float4*)(out + (size_t)i * FOUT + 8 * c);
            op[0] = make_float4(r[0], r[1], r[2], r[3]);
            op[1] = make_float4(r[4], r[5], r[6], r[7]);
        }
    } else {
        float* out = (float*)outv;
        constexpr int VC = FOUT / 8;               // valid lane-chunks (5 for FOUT=40)
        bool act = (c < VC);
        float v[8];
#pragma unroll
        for (int k = 0; k < 8; ++k) {
            float bv = bias[act ? 8 * c + k : 0];
            v[k] = act ? fmaf(acc[k], inv, bv) : -INFINITY;
        }
        float mx = v[0];
#pragma unroll
        for (int k = 1; k < 8; ++k) mx = fmaxf(mx, v[k]);
#pragma unroll
        for (int o = 1; o <= 4; o <<= 1) mx = fmaxf(mx, __shfl_xor(mx, o));  // within 8-lane group
        float es = 0.f;
        if (act) {
#pragma unroll
            for (int k = 0; k < 8; ++k) es += __expf(v[k] - mx);
        }
#pragma unroll
        for (int o = 1; o <= 4; o <<= 1) es += __shfl_xor(es, o);
        if (act) {
            float lse = mx + __logf(es);
            float4* op = (float4*)(out + (size_t)i * FOUT + 8 * c);
            op[0] = make_float4(v[0] - lse, v[1] - lse, v[2] - lse, v[3] - lse);
            op[1] = make_float4(v[4] - lse, v[5] - lse, v[6] - lse, v[7] - lse);
        }
    }
}

// ---------------- launch ----------------

extern "C" void kernel_launch(void* const* d_in, const int* in_sizes, int n_in,
                              void* d_out, int out_size, void* d_ws, size_t ws_size,
                              hipStream_t stream) {
    const float* x   = (const float*)d_in[0];
    const int* edges = (const int*)d_in[1];
    const float* W1  = (const float*)d_in[2];
    const float* av_s1 = (const float*)d_in[3];
    const float* av_d1 = (const float*)d_in[4];
    const float* b1  = (const float*)d_in[5];
    const float* W2  = (const float*)d_in[6];
    const float* av_s2 = (const float*)d_in[7];
    const float* av_d2 = (const float*)d_in[8];
    const float* b2  = (const float*)d_in[9];
    float* out = (float*)d_out;

    const int N  = in_sizes[0] / F_IN;
    const int E  = in_sizes[1] / 2;
    const int Et = E + N;
    const int NB = (N + 255) >> 8;

    char* p = (char*)d_ws;
    auto alloc = [&](size_t bytes) {
        char* q = p;
        p += (bytes + 255) & ~(size_t)255;
        return (void*)q;
    };
    unsigned short* h1 = (unsigned short*)alloc((size_t)N * F_H * 2);  // f16 [N][64]
    unsigned short* h2a = (unsigned short*)alloc((size_t)N * 32 * 2);  // T0: cols 0..31
    unsigned short* h2b = (unsigned short*)alloc((size_t)N * 8 * 2);   // T1: cols 32..39
    unsigned short* out1h = (unsigned short*)alloc((size_t)N * F_H * 2);  // f16 agg1 output [N][64]
    float* as1    = (float*)alloc((size_t)N * 4);
    float* ad1    = (float*)alloc((size_t)N * 4);
    float* as2    = (float*)alloc((size_t)N * 4);
    float* ad2    = (float*)alloc((size_t)N * 4);
    int* rp       = (int*)alloc((size_t)(N + 1) * 4);
    int* bcnt     = (int*)alloc(NBMAX * 4);
    int* bbase    = (int*)alloc(NBMAX * 4);
    int* bcur     = (int*)alloc(NBMAX * 4);
    unsigned* binned = (unsigned*)alloc((size_t)Et * 4);
    int* csr      = (int*)alloc((size_t)Et * 4);
    unsigned short* WhiT = (unsigned short*)alloc((size_t)F_H * F_IN * 2);
    unsigned short* WloT = (unsigned short*)alloc((size_t)F_H * F_IN * 2);
    (void)n_in; (void)out_size; (void)ws_size;

    const int* srcs = edges;
    const int* dsts = edges + E;

    hipMemsetAsync(bcnt, 0, NBMAX * 4, stream);

    k_wsplit<<<(F_IN * F_H + 255) / 256, 256, 0, stream>>>(W1, WhiT, WloT);
    k_binA<<<(Et + 2047) / 2048, 256, 0, stream>>>(dsts, bcnt, E, Et, NB);
    k_binB<<<1, NBMAX, 0, stream>>>(bcnt, bbase, bcur, rp, NB, N, Et);
    k_binC<<<(Et + CHUNK - 1) / CHUNK, 256, 0, stream>>>(srcs, dsts, bcur, binned, E, Et, NB);
    k_binD<<<NB, 256, 0, stream>>>(binned, bbase, bcur, rp, csr, N);

    k_gemm1m<<<(N + 63) / 64, 256, 0, stream>>>(x, WhiT, WloT, av_s1, av_d1, h1, as1, ad1, N);
    int gAgg = (N + 31) / 32;
    k_agg<F_H, false, true, false, true><<<gAgg, 256, 0, stream>>>(
        rp, csr, as1, ad1, (const uint4*)h1, nullptr, b1, out1h, N);
    k_gemm2<<<(N + 63) / 64, 256, 0, stream>>>(out1h, W2, av_s2, av_d2, h2a, h2b, as2, ad2, N);
    k_agg<F_O, true, false, true, false><<<gAgg, 256, 0, stream>>>(
        rp, csr, as2, ad2, (const uint4*)h2a, (const uint4*)h2b, b2, out, N);
}